// Round 2
// baseline (1522.568 us; speedup 1.0000x reference)
//
#include <hip/hip_runtime.h>

#define AS1 __attribute__((address_space(1)))
#define AS3 __attribute__((address_space(3)))

typedef __attribute__((ext_vector_type(8))) short short8;
typedef __attribute__((ext_vector_type(4))) float floatx4;

__device__ __forceinline__ float b2f(ushort u) {
  union { unsigned int i; float f; } x; x.i = ((unsigned int)u) << 16; return x.f;
}
__device__ __forceinline__ ushort f2b(float f) {
  union { float f; unsigned int i; } x; x.f = f;
  unsigned int r = (x.i + 0x7fffu + ((x.i >> 16) & 1u)) >> 16;
  return (ushort)r;
}

#define GF_RELU 1

// ---------------------------------------------------------------------------
// Flash attention: attn[b][i][:] = softmax(q_i . K^T / 8) @ V, never
// materializing scores. Block = 512 thr (8 waves), Q-tile = 64 rows.
// Wave w: S-tile rows (w&3)*16, cols (w>>2)*32; O-slice cols w*64..w*64+64.
//
// v3 (vs v1=287us, v2=292us, both MfmaUtil ~20%, Occupancy 23% = 1 blk/CU):
//  v2 proved intra-block pipelining is not the lever — removing 128KB/iter of
//  Vt LDS traffic + a barrier changed nothing. Regime is latency-bound at
//  2 waves/SIMD with a lockstep barrier'd chain. So v3 targets OCCUPANCY:
//  - single-buffered K tile (64KB) + P (8KB) + lsum = 73,984 B LDS
//    -> 2 blocks/CU, 4 waves/SIMD: cross-block overlap hides stage drains,
//    barrier waits, and dependent-MFMA chains (m114 wave-level overlap).
//  - V stays out of LDS (zero cross-wave reuse), loaded L2->regs each iter,
//    issued before the stage-drain barrier so latency hides under QK^T.
//  - __launch_bounds__(512,4) pins VGPR <= 128 (v2 measured 128).
//  K staged via global_load_lds(16B) with 16B-chunk XOR swizzle (keyed by
//  row&7) applied on the SOURCE index. P via LDS (same swizzle) for the
//  MFMA C->A layout turn. No max-subtraction (|s|<=~6).
// ---------------------------------------------------------------------------
__global__ __launch_bounds__(512, 4) void flash_attn(
    const ushort* __restrict__ qkv,   // [4*4096][1536]: q cols 0.., k cols 512..
    const ushort* __restrict__ vts,   // [4][512][4096]  (V^T per batch)
    ushort* __restrict__ attn)        // [4*4096][512]
{
  extern __shared__ __align__(16) ushort smem[];
  ushort* Ks  = smem;                 // 64*512 = 32768 elems (65536 B)
  ushort* P   = Ks + 64 * 512;        // 64*64  =  4096 elems (8192 B)
  float* lsum = (float*)(P + 64 * 64);// 64 floats (256 B)   -> 73,984 B total

  const int tid  = threadIdx.x;
  const int w    = tid >> 6;          // 0..7
  const int lane = tid & 63;
  const int lo   = lane & 15;
  const int quad = lane >> 4;

  // batch -> XCD-pair mapping: b = (id&7)>>1 so same-batch blocks share L2.
  const int id = blockIdx.x;
  const int b  = (id & 7) >> 1;
  const int qt = ((id >> 3) << 1) | (id & 1);
  const size_t qrow0 = (size_t)b * 4096 + (size_t)qt * 64;

  const ushort* Qg = qkv + qrow0 * 1536;
  const ushort* Kg = qkv + (size_t)b * 4096 * 1536 + 512;
  const ushort* Vg = vts + (size_t)b * 512 * 4096;

  const int sr = w & 3;               // S row-block
  const int sc = w >> 2;              // S col-half

  // Q fragments for this wave's S rows: A[m=lo][k=t*32+quad*8+j].
  short8 qf[16];
#pragma unroll
  for (int t = 0; t < 16; ++t)
    qf[t] = *(const short8*)(Qg + (size_t)(sr * 16 + lo) * 1536 + t * 32 + quad * 8);

  floatx4 oacc[4][4] = {};            // O rows 64 (mt), cols w*64+nt*16+lo
  float lpart[2][4] = {};             // rowsum partials [nt][r]

  if (tid < 64) lsum[tid] = 0.f;

  for (int j = 0; j < 4096; j += 64) {
    __syncthreads();  // [A] prev-iter K readers (QK^T) and P readers (PV) done

    // Stage K-tile: slot s=tid+512k -> pos=s>>6, sl=s&63; src chunk = sl^(pos&7).
#pragma unroll
    for (int k = 0; k < 8; ++k) {
      const int s = tid + k * 512;
      const int pos = s >> 6, sl = s & 63;
      const ushort* src = Kg + (size_t)(j + pos) * 1536 + ((sl ^ (pos & 7)) << 3);
      __builtin_amdgcn_global_load_lds((const AS1 void*)src, (AS3 void*)(Ks + s * 8), 16, 0, 0);
    }

    // V fragments for this tile: straight from L2 into registers (issued
    // before the drain barrier so their latency hides under QK^T).
    // B[k=kc*32+quad*8+jj][n=dc]; 16B contiguous per row of vts.
    short8 vf[2][4];
#pragma unroll
    for (int kc = 0; kc < 2; ++kc)
#pragma unroll
      for (int nt = 0; nt < 4; ++nt) {
        const int dc = w * 64 + nt * 16 + lo;
        vf[kc][nt] = *(const short8*)(Vg + (size_t)dc * 4096 + j + ((kc * 4 + quad) << 3));
      }

    __syncthreads();  // [B] vmcnt(0) drain: K-tile staged & visible

    // S = Q.K^T for this wave's tile (2 n-tiles, 16 k-chunks).
    floatx4 sacc[2] = {};
#pragma unroll
    for (int t = 0; t < 16; ++t)
#pragma unroll
      for (int nt = 0; nt < 2; ++nt) {
        const int kpos = sc * 32 + nt * 16 + lo;
        const short8 kf = *(const short8*)(Ks + ((size_t)kpos * 64 + ((t * 4 + quad) ^ (kpos & 7))) * 8);
        sacc[nt] = __builtin_amdgcn_mfma_f32_16x16x32_bf16(qf[t], kf, sacc[nt], 0, 0, 0);
      }

    // P = exp(s/8) -> LDS (swizzled); accumulate row-sums in regs.
#pragma unroll
    for (int nt = 0; nt < 2; ++nt)
#pragma unroll
      for (int r = 0; r < 4; ++r) {
        const float e = __expf(sacc[nt][r] * 0.125f);
        float rsum = e;
        rsum += __shfl_xor(rsum, 1, 64);
        rsum += __shfl_xor(rsum, 2, 64);
        rsum += __shfl_xor(rsum, 4, 64);
        rsum += __shfl_xor(rsum, 8, 64);
        lpart[nt][r] += rsum;
        const int row = sr * 16 + quad * 4 + r;
        const int col = sc * 32 + nt * 16 + lo;
        P[((size_t)row * 8 + ((col >> 3) ^ (row & 7))) * 8 + (col & 7)] = f2b(e);
      }
    __syncthreads();  // [C] P visible

    // O += P @ V: A from P (4 mt, 2 kc), B from registers (vf).
#pragma unroll
    for (int kc = 0; kc < 2; ++kc) {
      short8 pf[4];
#pragma unroll
      for (int mt = 0; mt < 4; ++mt) {
        const int row = mt * 16 + lo;
        pf[mt] = *(const short8*)(P + ((size_t)row * 8 + ((kc * 4 + quad) ^ (row & 7))) * 8);
      }
#pragma unroll
      for (int mt = 0; mt < 4; ++mt)
#pragma unroll
        for (int nt = 0; nt < 4; ++nt)
          oacc[mt][nt] = __builtin_amdgcn_mfma_f32_16x16x32_bf16(pf[mt], vf[kc][nt], oacc[mt][nt], 0, 0, 0);
    }
  }

  __syncthreads();
  if (lo == 0) {
#pragma unroll
    for (int nt = 0; nt < 2; ++nt)
#pragma unroll
      for (int r = 0; r < 4; ++r)
        atomicAdd(&lsum[sr * 16 + quad * 4 + r], lpart[nt][r]);
  }
  __syncthreads();

#pragma unroll
  for (int mt = 0; mt < 4; ++mt)
#pragma unroll
    for (int r = 0; r < 4; ++r) {
      const int row = mt * 16 + quad * 4 + r;
      const float inv = 1.f / lsum[row];
#pragma unroll
      for (int nt = 0; nt < 4; ++nt)
        attn[(qrow0 + row) * 512 + w * 64 + nt * 16 + lo] = f2b(oacc[mt][nt][r] * inv);
    }
}

// ---------------------------------------------------------------------------
// Async NT GEMM, flat grid with XCD swizzle (Wu / FF1 / FF2).
// ---------------------------------------------------------------------------
__global__ __launch_bounds__(256) void gemm_async(
    const ushort* __restrict__ A, const ushort* __restrict__ Bt,
    const float* __restrict__ bias, ushort* __restrict__ C,
    int N, int K, int lda, int ldb,
    int lg_gx, int lg_gy, float scale, int flags)
{
  __shared__ __align__(16) ushort As[128 * 32];
  __shared__ __align__(16) ushort Bs[128 * 32];

  const int id = blockIdx.x;
  const int r8 = id & 7;
  const int s  = id >> 3;
  const int bx = s & ((1 << lg_gx) - 1);
  const int j  = r8 + ((s >> lg_gx) << 3);
  const int by = j & ((1 << lg_gy) - 1);

  const int tid  = threadIdx.x;
  const int w    = tid >> 6;
  const int lane = tid & 63;
  const int lo   = lane & 15;
  const int quad = lane >> 4;
  const int m0   = by * 128;
  const int n0   = bx * 128;
  const int wm   = (w & 1) * 64;
  const int wn   = (w >> 1) * 64;

  const int i0 = tid, i1 = tid + 256;
  const ushort* ga0 = A  + (size_t)(m0 + (i0 >> 2)) * lda + ((i0 & 3) << 3);
  const ushort* ga1 = A  + (size_t)(m0 + (i1 >> 2)) * lda + ((i1 & 3) << 3);
  const ushort* gb0 = Bt + (size_t)(n0 + (i0 >> 2)) * ldb + ((i0 & 3) << 3);
  const ushort* gb1 = Bt + (size_t)(n0 + (i1 >> 2)) * ldb + ((i1 & 3) << 3);

  floatx4 acc[4][4] = {};

  for (int k0 = 0; k0 < K; k0 += 32) {
    __syncthreads();
    __builtin_amdgcn_global_load_lds((const AS1 void*)(ga0 + k0), (AS3 void*)(As + i0 * 8), 16, 0, 0);
    __builtin_amdgcn_global_load_lds((const AS1 void*)(ga1 + k0), (AS3 void*)(As + i1 * 8), 16, 0, 0);
    __builtin_amdgcn_global_load_lds((const AS1 void*)(gb0 + k0), (AS3 void*)(Bs + i0 * 8), 16, 0, 0);
    __builtin_amdgcn_global_load_lds((const AS1 void*)(gb1 + k0), (AS3 void*)(Bs + i1 * 8), 16, 0, 0);
    __syncthreads();

    short8 af[4], bf[4];
#pragma unroll
    for (int t = 0; t < 4; ++t) {
      af[t] = *(const short8*)(As + (wm + t * 16 + lo) * 32 + quad * 8);
      bf[t] = *(const short8*)(Bs + (wn + t * 16 + lo) * 32 + quad * 8);
    }
#pragma unroll
    for (int mt = 0; mt < 4; ++mt)
#pragma unroll
      for (int nt = 0; nt < 4; ++nt)
        acc[mt][nt] = __builtin_amdgcn_mfma_f32_16x16x32_bf16(af[mt], bf[nt], acc[mt][nt], 0, 0, 0);
  }

#pragma unroll
  for (int mt = 0; mt < 4; ++mt)
#pragma unroll
    for (int nt = 0; nt < 4; ++nt)
#pragma unroll
      for (int r = 0; r < 4; ++r) {
        int row = m0 + wm + mt * 16 + quad * 4 + r;
        int col = n0 + wn + nt * 16 + lo;
        float v = acc[mt][nt][r] * scale;
        if (bias) v += bias[col];
        if (flags & GF_RELU) v = fmaxf(v, 0.f);
        C[(size_t)row * N + col] = f2b(v);
      }
}

// ---------------------------------------------------------------------------
// Sync NT GEMM with fp32 A (cast in staging) — fused QKV projection.
// ---------------------------------------------------------------------------
__global__ __launch_bounds__(256) void gemm_sync_f32a(
    const float* __restrict__ Af, const ushort* __restrict__ Bt,
    const float* __restrict__ bias, ushort* __restrict__ C,
    int N, int K)
{
  __shared__ __align__(16) ushort As[128 * 32];
  __shared__ __align__(16) ushort Bs[128 * 32];

  const int tid  = threadIdx.x;
  const int w    = tid >> 6;
  const int lane = tid & 63;
  const int lo   = lane & 15;
  const int quad = lane >> 4;
  const int m0   = blockIdx.y * 128;
  const int n0   = blockIdx.x * 128;
  const int wm   = (w & 1) * 64;
  const int wn   = (w >> 1) * 64;

  const int i0 = tid, i1 = tid + 256;
  const size_t aoff0 = (size_t)(m0 + (i0 >> 2)) * K + ((i0 & 3) << 3);
  const size_t aoff1 = (size_t)(m0 + (i1 >> 2)) * K + ((i1 & 3) << 3);
  const size_t boff0 = (size_t)(n0 + (i0 >> 2)) * K + ((i0 & 3) << 3);
  const size_t boff1 = (size_t)(n0 + (i1 >> 2)) * K + ((i1 & 3) << 3);

  floatx4 acc[4][4] = {};

  for (int k0 = 0; k0 < K; k0 += 32) {
    short8 va0, va1;
    const float4 a00 = *(const float4*)(Af + aoff0 + k0);
    const float4 a01 = *(const float4*)(Af + aoff0 + k0 + 4);
    const float4 a10 = *(const float4*)(Af + aoff1 + k0);
    const float4 a11 = *(const float4*)(Af + aoff1 + k0 + 4);
    va0[0] = (short)f2b(a00.x); va0[1] = (short)f2b(a00.y);
    va0[2] = (short)f2b(a00.z); va0[3] = (short)f2b(a00.w);
    va0[4] = (short)f2b(a01.x); va0[5] = (short)f2b(a01.y);
    va0[6] = (short)f2b(a01.z); va0[7] = (short)f2b(a01.w);
    va1[0] = (short)f2b(a10.x); va1[1] = (short)f2b(a10.y);
    va1[2] = (short)f2b(a10.z); va1[3] = (short)f2b(a10.w);
    va1[4] = (short)f2b(a11.x); va1[5] = (short)f2b(a11.y);
    va1[6] = (short)f2b(a11.z); va1[7] = (short)f2b(a11.w);
    const short8 vb0 = *(const short8*)(Bt + boff0 + k0);
    const short8 vb1 = *(const short8*)(Bt + boff1 + k0);
    __syncthreads();
    *(short8*)(As + i0 * 8) = va0;
    *(short8*)(As + i1 * 8) = va1;
    *(short8*)(Bs + i0 * 8) = vb0;
    *(short8*)(Bs + i1 * 8) = vb1;
    __syncthreads();

    short8 af[4], bf[4];
#pragma unroll
    for (int t = 0; t < 4; ++t) {
      af[t] = *(const short8*)(As + (wm + t * 16 + lo) * 32 + quad * 8);
      bf[t] = *(const short8*)(Bs + (wn + t * 16 + lo) * 32 + quad * 8);
    }
#pragma unroll
    for (int mt = 0; mt < 4; ++mt)
#pragma unroll
      for (int nt = 0; nt < 4; ++nt)
        acc[mt][nt] = __builtin_amdgcn_mfma_f32_16x16x32_bf16(af[mt], bf[nt], acc[mt][nt], 0, 0, 0);
  }

#pragma unroll
  for (int mt = 0; mt < 4; ++mt)
#pragma unroll
    for (int nt = 0; nt < 4; ++nt)
#pragma unroll
      for (int r = 0; r < 4; ++r) {
        int row = m0 + wm + mt * 16 + quad * 4 + r;
        int col = n0 + wn + nt * 16 + lo;
        C[(size_t)row * N + col] = f2b(acc[mt][nt][r] + bias[col]);
      }
}

// ---------------------------------------------------------------------------
__global__ void transpose_cast(const float* __restrict__ in, ushort* __restrict__ out,
                               int R, int C)
{
  __shared__ ushort t[64][65];
  const int r0 = blockIdx.y * 64, c0 = blockIdx.x * 64;
  const int tx = threadIdx.x, ty = threadIdx.y;
  for (int i = ty; i < 64; i += 4)
    t[i][tx] = f2b(in[(size_t)(r0 + i) * C + c0 + tx]);
  __syncthreads();
  for (int i = ty; i < 64; i += 4)
    out[(size_t)(c0 + i) * R + r0 + tx] = t[tx][i];
}

__global__ void transpose_bf(const ushort* __restrict__ in, ushort* __restrict__ out,
                             int R, int C, int ldin)
{
  __shared__ ushort t[64][65];
  const int r0 = blockIdx.y * 64, c0 = blockIdx.x * 64;
  const int tx = threadIdx.x, ty = threadIdx.y;
  for (int i = ty; i < 64; i += 4)
    t[i][tx] = in[(size_t)(r0 + i) * ldin + c0 + tx];
  __syncthreads();
  for (int i = ty; i < 64; i += 4)
    out[(size_t)(c0 + i) * R + r0 + tx] = t[tx][i];
}

__global__ void concat_bias(const float* __restrict__ a, const float* __restrict__ b,
                            const float* __restrict__ c, float* __restrict__ o)
{
  const int i = blockIdx.x * 256 + threadIdx.x;
  o[i] = (i < 512) ? a[i] : ((i < 1024) ? b[i - 512] : c[i - 1024]);
}

// ---------------------------------------------------------------------------
// out = LayerNorm(X + Y) * g + b. X fp32/bf16, Y bf16, out fp32/bf16.
// ---------------------------------------------------------------------------
__global__ __launch_bounds__(256) void ln_res(
    const void* __restrict__ Xv, int x_f32, const ushort* __restrict__ Y,
    const float* __restrict__ g, const float* __restrict__ b,
    void* __restrict__ outv, int o_f32)
{
  const int w = threadIdx.x >> 6, lane = threadIdx.x & 63;
  const size_t row = (size_t)blockIdx.x * 4 + w;
  const size_t base = row * 512 + lane * 8;

  float v[8];
  if (x_f32) {
    const float* X = (const float*)Xv + base;
    const float4 x0 = *(const float4*)(X), x1 = *(const float4*)(X + 4);
    v[0] = x0.x; v[1] = x0.y; v[2] = x0.z; v[3] = x0.w;
    v[4] = x1.x; v[5] = x1.y; v[6] = x1.z; v[7] = x1.w;
  } else {
    const short8 xv = *(const short8*)((const ushort*)Xv + base);
#pragma unroll
    for (int j = 0; j < 8; ++j) v[j] = b2f((ushort)xv[j]);
  }
  const short8 yv = *(const short8*)(Y + base);
  float s = 0.f, sq = 0.f;
#pragma unroll
  for (int j = 0; j < 8; ++j) {
    v[j] += b2f((ushort)yv[j]);
    s += v[j]; sq += v[j] * v[j];
  }
  for (int m = 1; m < 64; m <<= 1) {
    s  += __shfl_xor(s,  m, 64);
    sq += __shfl_xor(sq, m, 64);
  }
  const float mean = s * (1.f / 512.f);
  const float var  = sq * (1.f / 512.f) - mean * mean;
  const float rstd = rsqrtf(fmaxf(var, 0.f) + 1e-5f);

  const float4 g0 = *(const float4*)(g + lane * 8);
  const float4 g1 = *(const float4*)(g + lane * 8 + 4);
  const float4 b0 = *(const float4*)(b + lane * 8);
  const float4 b1 = *(const float4*)(b + lane * 8 + 4);
  const float gg[8] = {g0.x, g0.y, g0.z, g0.w, g1.x, g1.y, g1.z, g1.w};
  const float bb[8] = {b0.x, b0.y, b0.z, b0.w, b1.x, b1.y, b1.z, b1.w};

  if (o_f32) {
    float* o = (float*)outv + base;
#pragma unroll
    for (int j = 0; j < 8; ++j) o[j] = (v[j] - mean) * rstd * gg[j] + bb[j];
  } else {
    ushort* o = (ushort*)outv + base;
    short8 ov;
#pragma unroll
    for (int j = 0; j < 8; ++j) ov[j] = (short)f2b((v[j] - mean) * rstd * gg[j] + bb[j]);
    *(short8*)o = ov;
  }
}

// ---------------------------------------------------------------------------
extern "C" void kernel_launch(void* const* d_in, const int* in_sizes, int n_in,
                              void* d_out, int out_size, void* d_ws, size_t ws_size,
                              hipStream_t stream)
{
  const float* x    = (const float*)d_in[0];
  const float* Wq_w = (const float*)d_in[1];
  const float* Wq_b = (const float*)d_in[2];
  const float* Wk_w = (const float*)d_in[3];
  const float* Wk_b = (const float*)d_in[4];
  const float* Wv_w = (const float*)d_in[5];
  const float* Wv_b = (const float*)d_in[6];
  const float* Wu_w = (const float*)d_in[7];
  const float* Wu_b = (const float*)d_in[8];
  const float* g1   = (const float*)d_in[9];
  const float* b1   = (const float*)d_in[10];
  const float* f1w  = (const float*)d_in[11];
  const float* f1b  = (const float*)d_in[12];
  const float* f2w  = (const float*)d_in[13];
  const float* f2bv = (const float*)d_in[14];
  const float* g2   = (const float*)d_in[15];
  const float* b2   = (const float*)d_in[16];

  // Workspace (byte offsets; peak 207.6 MB <= 224.4 MB known floor).
  char* wsb = (char*)d_ws;
  ushort* wqkvt = (ushort*)(wsb + 0);             // 1536x512   ends   1,572,864
  ushort* wut   = (ushort*)(wsb + 1572864);       //  512x512   ends   2,097,152
  ushort* f1t   = (ushort*)(wsb + 2097152);       // 2048x512   ends   4,194,304
  ushort* f2t   = (ushort*)(wsb + 4194304);       //  512x2048  ends   6,291,456
  float*  bqkv  = (float*) (wsb + 6291456);       // 1536 f32   ends   6,297,600
  ushort* qkv   = (ushort*)(wsb + 6297600);       // 16384x1536 ends  56,629,248
  ushort* vts   = (ushort*)(wsb + 56629248);      // 4x512x4096 ends  73,406,464
  ushort* attn  = (ushort*)(wsb + 73406464);      // 16384x512  ends  90,183,680
  ushort* uni   = (ushort*)(wsb + 90183680);      // 16384x512  ends 106,960,896
  ushort* h     = (ushort*)(wsb + 106960896);     // 16384x512  ends 123,738,112
  ushort* mid   = (ushort*)(wsb + 123738112);     // 16384x2048 ends 190,846,976
  ushort* ffo   = (ushort*)(wsb + 190846976);     // 16384x512  ends 207,624,192

  const dim3 tb(64, 4);
  transpose_cast<<<dim3(8, 8),  tb, 0, stream>>>(Wq_w, wqkvt,              512, 512);
  transpose_cast<<<dim3(8, 8),  tb, 0, stream>>>(Wk_w, wqkvt + 512 * 512,  512, 512);
  transpose_cast<<<dim3(8, 8),  tb, 0, stream>>>(Wv_w, wqkvt + 1024 * 512, 512, 512);
  transpose_cast<<<dim3(8, 8),  tb, 0, stream>>>(Wu_w, wut, 512, 512);
  transpose_cast<<<dim3(32, 8), tb, 0, stream>>>(f1w, f1t, 512, 2048);
  transpose_cast<<<dim3(8, 32), tb, 0, stream>>>(f2w, f2t, 2048, 512);
  concat_bias<<<6, 256, 0, stream>>>(Wq_b, Wk_b, Wv_b, bqkv);

  // Fused QKV: qkv[16384][1536] = x @ Wqkv^T + b.
  gemm_sync_f32a<<<dim3(12, 128), 256, 0, stream>>>(x, wqkvt, bqkv, qkv, 1536, 512);

  // V^T per batch from strided v (qkv cols 1024..1535).
  for (int b = 0; b < 4; ++b)
    transpose_bf<<<dim3(8, 64), tb, 0, stream>>>(
        qkv + (size_t)b * 4096 * 1536 + 1024, vts + (size_t)b * 512 * 4096,
        4096, 512, 1536);

  // Flash attention (73,984 B dynamic LDS -> 2 blocks/CU).
  hipFuncSetAttribute((const void*)flash_attn,
                      hipFuncAttributeMaxDynamicSharedMemorySize, 73984);
  flash_attn<<<256, 512, 73984, stream>>>(qkv, vts, attn);

  // Output projection + residual LN1.
  gemm_async<<<512, 256, 0, stream>>>(attn, wut, Wu_b, uni,
      512, 512, 512, 512, 2, 7, 1.f, 0);
  ln_res<<<4096, 256, 0, stream>>>(x, 1, uni, g1, b1, h, 0);

  // FFN + residual LN2 -> d_out (fp32).
  gemm_async<<<2048, 256, 0, stream>>>(h, f1t, f1b, mid,
      2048, 512, 512, 512, 4, 7, 1.f, GF_RELU);
  gemm_async<<<512, 256, 0, stream>>>(mid, f2t, f2bv, ffo,
      512, 2048, 2048, 2048, 2, 7, 1.f, 0);
  ln_res<<<4096, 256, 0, stream>>>(h, 0, ffo, g2, b2, d_out, 1);
}

// Round 3
// 848.783 us; speedup vs baseline: 1.7938x; 1.7938x over previous
//
#include <hip/hip_runtime.h>

#define AS1 __attribute__((address_space(1)))
#define AS3 __attribute__((address_space(3)))

typedef __attribute__((ext_vector_type(8))) short short8;
typedef __attribute__((ext_vector_type(4))) float floatx4;

__device__ __forceinline__ float b2f(ushort u) {
  union { unsigned int i; float f; } x; x.i = ((unsigned int)u) << 16; return x.f;
}
__device__ __forceinline__ ushort f2b(float f) {
  union { float f; unsigned int i; } x; x.f = f;
  unsigned int r = (x.i + 0x7fffu + ((x.i >> 16) & 1u)) >> 16;
  return (ushort)r;
}

#define GF_RELU 1

// ---------------------------------------------------------------------------
// Flash attention: attn[b][i][:] = softmax(q_i . K^T / 8) @ V, never
// materializing scores.
//
// v4 (vs v1=287us, v2=292us, v3=1145us):
//  v3 post-mortem: (a) __launch_bounds__(512,4) acts as min-BLOCKS/CU=4 ->
//  VGPR cap 64 -> 3GB spill traffic (FETCH 2.15GB); (b) grid was 256 blocks
//  on 256 CUs, so 2 blocks/CU was impossible no matter what. v4:
//  - Q-tile 32 rows -> grid = 512 blocks -> 2 blocks/CU schedulable.
//  - LDS = K(64KB) + P(4KB) + lsum = 69,760B; x2 = 139.5KB <= 160KB.
//  - per-wave state halved: oacc[2][4]=32 regs; persistent qf(64)+oacc(32)
//    = 96 < 128 cap from __launch_bounds__(512,2) (observed: v1/v2 hit
//    exactly 128 with MORE pressure). No spill expected.
//  - 8 waves: QK^T wave (sr=w&1, sc=w>>1) computes one 16x16 S tile
//    (16-chunk MFMA chain); PV wave owns O cols w*64..+64 (all 32 rows).
//  - V never staged in LDS (no cross-wave reuse): L2 -> regs, issued before
//    the stage-drain barrier so latency hides under QK^T.
//  K staged via global_load_lds(16B) with 16B-chunk XOR swizzle (keyed by
//  row&7) on the SOURCE index. P via LDS (same swizzle) for the MFMA C->A
//  layout turn. No max-subtraction (|s|<=~6).
// ---------------------------------------------------------------------------
__global__ __launch_bounds__(512, 2) void flash_attn(
    const ushort* __restrict__ qkv,   // [4*4096][1536]: q cols 0.., k cols 512..
    const ushort* __restrict__ vts,   // [4][512][4096]  (V^T per batch)
    ushort* __restrict__ attn)        // [4*4096][512]
{
  extern __shared__ __align__(16) ushort smem[];
  ushort* Ks  = smem;                 // 64*512 = 32768 elems (65536 B)
  ushort* P   = Ks + 64 * 512;        // 32*64  =  2048 elems (4096 B)
  float* lsum = (float*)(P + 32 * 64);// 32 floats (128 B)  -> 69,760 B total

  const int tid  = threadIdx.x;
  const int w    = tid >> 6;          // 0..7
  const int lane = tid & 63;
  const int lo   = lane & 15;
  const int quad = lane >> 4;

  // batch -> XCD-pair mapping: b = (id&7)>>1 so same-batch blocks share L2.
  const int id = blockIdx.x;          // 0..511
  const int b  = (id & 7) >> 1;
  const int qt = ((id >> 3) << 1) | (id & 1);   // 0..127
  const size_t qrow0 = (size_t)b * 4096 + (size_t)qt * 32;

  const ushort* Qg = qkv + qrow0 * 1536;
  const ushort* Kg = qkv + (size_t)b * 4096 * 1536 + 512;
  const ushort* Vg = vts + (size_t)b * 512 * 4096;

  const int sr = w & 1;               // S row-block (0..1)
  const int sc = w >> 1;              // S col-quarter (0..3)

  // Q fragments for this wave's S rows: A[m=lo][k=t*32+quad*8+j].
  short8 qf[16];
#pragma unroll
  for (int t = 0; t < 16; ++t)
    qf[t] = *(const short8*)(Qg + (size_t)(sr * 16 + lo) * 1536 + t * 32 + quad * 8);

  floatx4 oacc[2][4] = {};            // O rows 32 (mt), cols w*64+nt*16+lo
  float lpart[4] = {};                // rowsum partials [r]

  if (tid < 32) lsum[tid] = 0.f;

  for (int j = 0; j < 4096; j += 64) {
    __syncthreads();  // [A] prev-iter K readers (QK^T) and P readers (PV) done

    // Stage K-tile: slot s=tid+512k -> pos=s>>6, sl=s&63; src chunk = sl^(pos&7).
#pragma unroll
    for (int k = 0; k < 8; ++k) {
      const int s = tid + k * 512;
      const int pos = s >> 6, sl = s & 63;
      const ushort* src = Kg + (size_t)(j + pos) * 1536 + ((sl ^ (pos & 7)) << 3);
      __builtin_amdgcn_global_load_lds((const AS1 void*)src, (AS3 void*)(Ks + s * 8), 16, 0, 0);
    }

    // V fragments: straight from L2 into registers (issued before the drain
    // barrier so their latency hides under QK^T).
    short8 vf[2][4];
#pragma unroll
    for (int kc = 0; kc < 2; ++kc)
#pragma unroll
      for (int nt = 0; nt < 4; ++nt) {
        const int dc = w * 64 + nt * 16 + lo;
        vf[kc][nt] = *(const short8*)(Vg + (size_t)dc * 4096 + j + ((kc * 4 + quad) << 3));
      }

    __syncthreads();  // [B] vmcnt(0) drain: K-tile staged & visible

    // S = Q.K^T: one 16x16 tile per wave (cols sc*16..+16), 16 k-chunks.
    floatx4 sacc = {};
    const int kpos = sc * 16 + lo;
#pragma unroll
    for (int t = 0; t < 16; ++t) {
      const short8 kf = *(const short8*)(Ks + ((size_t)kpos * 64 + ((t * 4 + quad) ^ (kpos & 7))) * 8);
      sacc = __builtin_amdgcn_mfma_f32_16x16x32_bf16(qf[t], kf, sacc, 0, 0, 0);
    }

    // P = exp(s/8) -> LDS (swizzled); accumulate row-sum partials in regs.
#pragma unroll
    for (int r = 0; r < 4; ++r) {
      const float e = __expf(sacc[r] * 0.125f);
      float rsum = e;
      rsum += __shfl_xor(rsum, 1, 64);
      rsum += __shfl_xor(rsum, 2, 64);
      rsum += __shfl_xor(rsum, 4, 64);
      rsum += __shfl_xor(rsum, 8, 64);
      lpart[r] += rsum;
      const int row = sr * 16 + quad * 4 + r;
      const int col = sc * 16 + lo;
      P[((size_t)row * 8 + ((col >> 3) ^ (row & 7))) * 8 + (col & 7)] = f2b(e);
    }
    __syncthreads();  // [C] P visible

    // O += P @ V: A from P (2 mt, 2 kc), B from registers (vf).
#pragma unroll
    for (int kc = 0; kc < 2; ++kc) {
      short8 pf[2];
#pragma unroll
      for (int mt = 0; mt < 2; ++mt) {
        const int row = mt * 16 + lo;
        pf[mt] = *(const short8*)(P + ((size_t)row * 8 + ((kc * 4 + quad) ^ (row & 7))) * 8);
      }
#pragma unroll
      for (int mt = 0; mt < 2; ++mt)
#pragma unroll
        for (int nt = 0; nt < 4; ++nt)
          oacc[mt][nt] = __builtin_amdgcn_mfma_f32_16x16x32_bf16(pf[mt], vf[kc][nt], oacc[mt][nt], 0, 0, 0);
    }
  }

  __syncthreads();
  if (lo == 0) {
#pragma unroll
    for (int r = 0; r < 4; ++r)
      atomicAdd(&lsum[sr * 16 + quad * 4 + r], lpart[r]);
  }
  __syncthreads();

#pragma unroll
  for (int mt = 0; mt < 2; ++mt)
#pragma unroll
    for (int r = 0; r < 4; ++r) {
      const int row = mt * 16 + quad * 4 + r;
      const float inv = 1.f / lsum[row];
#pragma unroll
      for (int nt = 0; nt < 4; ++nt)
        attn[(qrow0 + row) * 512 + w * 64 + nt * 16 + lo] = f2b(oacc[mt][nt][r] * inv);
    }
}

// ---------------------------------------------------------------------------
// Async NT GEMM, flat grid with XCD swizzle (Wu / FF1 / FF2).
// ---------------------------------------------------------------------------
__global__ __launch_bounds__(256) void gemm_async(
    const ushort* __restrict__ A, const ushort* __restrict__ Bt,
    const float* __restrict__ bias, ushort* __restrict__ C,
    int N, int K, int lda, int ldb,
    int lg_gx, int lg_gy, float scale, int flags)
{
  __shared__ __align__(16) ushort As[128 * 32];
  __shared__ __align__(16) ushort Bs[128 * 32];

  const int id = blockIdx.x;
  const int r8 = id & 7;
  const int s  = id >> 3;
  const int bx = s & ((1 << lg_gx) - 1);
  const int j  = r8 + ((s >> lg_gx) << 3);
  const int by = j & ((1 << lg_gy) - 1);

  const int tid  = threadIdx.x;
  const int w    = tid >> 6;
  const int lane = tid & 63;
  const int lo   = lane & 15;
  const int quad = lane >> 4;
  const int m0   = by * 128;
  const int n0   = bx * 128;
  const int wm   = (w & 1) * 64;
  const int wn   = (w >> 1) * 64;

  const int i0 = tid, i1 = tid + 256;
  const ushort* ga0 = A  + (size_t)(m0 + (i0 >> 2)) * lda + ((i0 & 3) << 3);
  const ushort* ga1 = A  + (size_t)(m0 + (i1 >> 2)) * lda + ((i1 & 3) << 3);
  const ushort* gb0 = Bt + (size_t)(n0 + (i0 >> 2)) * ldb + ((i0 & 3) << 3);
  const ushort* gb1 = Bt + (size_t)(n0 + (i1 >> 2)) * ldb + ((i1 & 3) << 3);

  floatx4 acc[4][4] = {};

  for (int k0 = 0; k0 < K; k0 += 32) {
    __syncthreads();
    __builtin_amdgcn_global_load_lds((const AS1 void*)(ga0 + k0), (AS3 void*)(As + i0 * 8), 16, 0, 0);
    __builtin_amdgcn_global_load_lds((const AS1 void*)(ga1 + k0), (AS3 void*)(As + i1 * 8), 16, 0, 0);
    __builtin_amdgcn_global_load_lds((const AS1 void*)(gb0 + k0), (AS3 void*)(Bs + i0 * 8), 16, 0, 0);
    __builtin_amdgcn_global_load_lds((const AS1 void*)(gb1 + k0), (AS3 void*)(Bs + i1 * 8), 16, 0, 0);
    __syncthreads();

    short8 af[4], bf[4];
#pragma unroll
    for (int t = 0; t < 4; ++t) {
      af[t] = *(const short8*)(As + (wm + t * 16 + lo) * 32 + quad * 8);
      bf[t] = *(const short8*)(Bs + (wn + t * 16 + lo) * 32 + quad * 8);
    }
#pragma unroll
    for (int mt = 0; mt < 4; ++mt)
#pragma unroll
      for (int nt = 0; nt < 4; ++nt)
        acc[mt][nt] = __builtin_amdgcn_mfma_f32_16x16x32_bf16(af[mt], bf[nt], acc[mt][nt], 0, 0, 0);
  }

#pragma unroll
  for (int mt = 0; mt < 4; ++mt)
#pragma unroll
    for (int nt = 0; nt < 4; ++nt)
#pragma unroll
      for (int r = 0; r < 4; ++r) {
        int row = m0 + wm + mt * 16 + quad * 4 + r;
        int col = n0 + wn + nt * 16 + lo;
        float v = acc[mt][nt][r] * scale;
        if (bias) v += bias[col];
        if (flags & GF_RELU) v = fmaxf(v, 0.f);
        C[(size_t)row * N + col] = f2b(v);
      }
}

// ---------------------------------------------------------------------------
// Sync NT GEMM with fp32 A (cast in staging) — fused QKV projection.
// ---------------------------------------------------------------------------
__global__ __launch_bounds__(256) void gemm_sync_f32a(
    const float* __restrict__ Af, const ushort* __restrict__ Bt,
    const float* __restrict__ bias, ushort* __restrict__ C,
    int N, int K)
{
  __shared__ __align__(16) ushort As[128 * 32];
  __shared__ __align__(16) ushort Bs[128 * 32];

  const int tid  = threadIdx.x;
  const int w    = tid >> 6;
  const int lane = tid & 63;
  const int lo   = lane & 15;
  const int quad = lane >> 4;
  const int m0   = blockIdx.y * 128;
  const int n0   = blockIdx.x * 128;
  const int wm   = (w & 1) * 64;
  const int wn   = (w >> 1) * 64;

  const int i0 = tid, i1 = tid + 256;
  const size_t aoff0 = (size_t)(m0 + (i0 >> 2)) * K + ((i0 & 3) << 3);
  const size_t aoff1 = (size_t)(m0 + (i1 >> 2)) * K + ((i1 & 3) << 3);
  const size_t boff0 = (size_t)(n0 + (i0 >> 2)) * K + ((i0 & 3) << 3);
  const size_t boff1 = (size_t)(n0 + (i1 >> 2)) * K + ((i1 & 3) << 3);

  floatx4 acc[4][4] = {};

  for (int k0 = 0; k0 < K; k0 += 32) {
    short8 va0, va1;
    const float4 a00 = *(const float4*)(Af + aoff0 + k0);
    const float4 a01 = *(const float4*)(Af + aoff0 + k0 + 4);
    const float4 a10 = *(const float4*)(Af + aoff1 + k0);
    const float4 a11 = *(const float4*)(Af + aoff1 + k0 + 4);
    va0[0] = (short)f2b(a00.x); va0[1] = (short)f2b(a00.y);
    va0[2] = (short)f2b(a00.z); va0[3] = (short)f2b(a00.w);
    va0[4] = (short)f2b(a01.x); va0[5] = (short)f2b(a01.y);
    va0[6] = (short)f2b(a01.z); va0[7] = (short)f2b(a01.w);
    va1[0] = (short)f2b(a10.x); va1[1] = (short)f2b(a10.y);
    va1[2] = (short)f2b(a10.z); va1[3] = (short)f2b(a10.w);
    va1[4] = (short)f2b(a11.x); va1[5] = (short)f2b(a11.y);
    va1[6] = (short)f2b(a11.z); va1[7] = (short)f2b(a11.w);
    const short8 vb0 = *(const short8*)(Bt + boff0 + k0);
    const short8 vb1 = *(const short8*)(Bt + boff1 + k0);
    __syncthreads();
    *(short8*)(As + i0 * 8) = va0;
    *(short8*)(As + i1 * 8) = va1;
    *(short8*)(Bs + i0 * 8) = vb0;
    *(short8*)(Bs + i1 * 8) = vb1;
    __syncthreads();

    short8 af[4], bf[4];
#pragma unroll
    for (int t = 0; t < 4; ++t) {
      af[t] = *(const short8*)(As + (wm + t * 16 + lo) * 32 + quad * 8);
      bf[t] = *(const short8*)(Bs + (wn + t * 16 + lo) * 32 + quad * 8);
    }
#pragma unroll
    for (int mt = 0; mt < 4; ++mt)
#pragma unroll
      for (int nt = 0; nt < 4; ++nt)
        acc[mt][nt] = __builtin_amdgcn_mfma_f32_16x16x32_bf16(af[mt], bf[nt], acc[mt][nt], 0, 0, 0);
  }

#pragma unroll
  for (int mt = 0; mt < 4; ++mt)
#pragma unroll
    for (int nt = 0; nt < 4; ++nt)
#pragma unroll
      for (int r = 0; r < 4; ++r) {
        int row = m0 + wm + mt * 16 + quad * 4 + r;
        int col = n0 + wn + nt * 16 + lo;
        C[(size_t)row * N + col] = f2b(acc[mt][nt][r] + bias[col]);
      }
}

// ---------------------------------------------------------------------------
__global__ void transpose_cast(const float* __restrict__ in, ushort* __restrict__ out,
                               int R, int C)
{
  __shared__ ushort t[64][65];
  const int r0 = blockIdx.y * 64, c0 = blockIdx.x * 64;
  const int tx = threadIdx.x, ty = threadIdx.y;
  for (int i = ty; i < 64; i += 4)
    t[i][tx] = f2b(in[(size_t)(r0 + i) * C + c0 + tx]);
  __syncthreads();
  for (int i = ty; i < 64; i += 4)
    out[(size_t)(c0 + i) * R + r0 + tx] = t[tx][i];
}

__global__ void transpose_bf(const ushort* __restrict__ in, ushort* __restrict__ out,
                             int R, int C, int ldin)
{
  __shared__ ushort t[64][65];
  const int r0 = blockIdx.y * 64, c0 = blockIdx.x * 64;
  const int tx = threadIdx.x, ty = threadIdx.y;
  for (int i = ty; i < 64; i += 4)
    t[i][tx] = in[(size_t)(r0 + i) * ldin + c0 + tx];
  __syncthreads();
  for (int i = ty; i < 64; i += 4)
    out[(size_t)(c0 + i) * R + r0 + tx] = t[tx][i];
}

__global__ void concat_bias(const float* __restrict__ a, const float* __restrict__ b,
                            const float* __restrict__ c, float* __restrict__ o)
{
  const int i = blockIdx.x * 256 + threadIdx.x;
  o[i] = (i < 512) ? a[i] : ((i < 1024) ? b[i - 512] : c[i - 1024]);
}

// ---------------------------------------------------------------------------
// out = LayerNorm(X + Y) * g + b. X fp32/bf16, Y bf16, out fp32/bf16.
// ---------------------------------------------------------------------------
__global__ __launch_bounds__(256) void ln_res(
    const void* __restrict__ Xv, int x_f32, const ushort* __restrict__ Y,
    const float* __restrict__ g, const float* __restrict__ b,
    void* __restrict__ outv, int o_f32)
{
  const int w = threadIdx.x >> 6, lane = threadIdx.x & 63;
  const size_t row = (size_t)blockIdx.x * 4 + w;
  const size_t base = row * 512 + lane * 8;

  float v[8];
  if (x_f32) {
    const float* X = (const float*)Xv + base;
    const float4 x0 = *(const float4*)(X), x1 = *(const float4*)(X + 4);
    v[0] = x0.x; v[1] = x0.y; v[2] = x0.z; v[3] = x0.w;
    v[4] = x1.x; v[5] = x1.y; v[6] = x1.z; v[7] = x1.w;
  } else {
    const short8 xv = *(const short8*)((const ushort*)Xv + base);
#pragma unroll
    for (int j = 0; j < 8; ++j) v[j] = b2f((ushort)xv[j]);
  }
  const short8 yv = *(const short8*)(Y + base);
  float s = 0.f, sq = 0.f;
#pragma unroll
  for (int j = 0; j < 8; ++j) {
    v[j] += b2f((ushort)yv[j]);
    s += v[j]; sq += v[j] * v[j];
  }
  for (int m = 1; m < 64; m <<= 1) {
    s  += __shfl_xor(s,  m, 64);
    sq += __shfl_xor(sq, m, 64);
  }
  const float mean = s * (1.f / 512.f);
  const float var  = sq * (1.f / 512.f) - mean * mean;
  const float rstd = rsqrtf(fmaxf(var, 0.f) + 1e-5f);

  const float4 g0 = *(const float4*)(g + lane * 8);
  const float4 g1 = *(const float4*)(g + lane * 8 + 4);
  const float4 b0 = *(const float4*)(b + lane * 8);
  const float4 b1 = *(const float4*)(b + lane * 8 + 4);
  const float gg[8] = {g0.x, g0.y, g0.z, g0.w, g1.x, g1.y, g1.z, g1.w};
  const float bb[8] = {b0.x, b0.y, b0.z, b0.w, b1.x, b1.y, b1.z, b1.w};

  if (o_f32) {
    float* o = (float*)outv + base;
#pragma unroll
    for (int j = 0; j < 8; ++j) o[j] = (v[j] - mean) * rstd * gg[j] + bb[j];
  } else {
    ushort* o = (ushort*)outv + base;
    short8 ov;
#pragma unroll
    for (int j = 0; j < 8; ++j) ov[j] = (short)f2b((v[j] - mean) * rstd * gg[j] + bb[j]);
    *(short8*)o = ov;
  }
}

// ---------------------------------------------------------------------------
extern "C" void kernel_launch(void* const* d_in, const int* in_sizes, int n_in,
                              void* d_out, int out_size, void* d_ws, size_t ws_size,
                              hipStream_t stream)
{
  const float* x    = (const float*)d_in[0];
  const float* Wq_w = (const float*)d_in[1];
  const float* Wq_b = (const float*)d_in[2];
  const float* Wk_w = (const float*)d_in[3];
  const float* Wk_b = (const float*)d_in[4];
  const float* Wv_w = (const float*)d_in[5];
  const float* Wv_b = (const float*)d_in[6];
  const float* Wu_w = (const float*)d_in[7];
  const float* Wu_b = (const float*)d_in[8];
  const float* g1   = (const float*)d_in[9];
  const float* b1   = (const float*)d_in[10];
  const float* f1w  = (const float*)d_in[11];
  const float* f1b  = (const float*)d_in[12];
  const float* f2w  = (const float*)d_in[13];
  const float* f2bv = (const float*)d_in[14];
  const float* g2   = (const float*)d_in[15];
  const float* b2   = (const float*)d_in[16];

  // Workspace (byte offsets; peak 207.6 MB <= 224.4 MB known floor).
  char* wsb = (char*)d_ws;
  ushort* wqkvt = (ushort*)(wsb + 0);             // 1536x512   ends   1,572,864
  ushort* wut   = (ushort*)(wsb + 1572864);       //  512x512   ends   2,097,152
  ushort* f1t   = (ushort*)(wsb + 2097152);       // 2048x512   ends   4,194,304
  ushort* f2t   = (ushort*)(wsb + 4194304);       //  512x2048  ends   6,291,456
  float*  bqkv  = (float*) (wsb + 6291456);       // 1536 f32   ends   6,297,600
  ushort* qkv   = (ushort*)(wsb + 6297600);       // 16384x1536 ends  56,629,248
  ushort* vts   = (ushort*)(wsb + 56629248);      // 4x512x4096 ends  73,406,464
  ushort* attn  = (ushort*)(wsb + 73406464);      // 16384x512  ends  90,183,680
  ushort* uni   = (ushort*)(wsb + 90183680);      // 16384x512  ends 106,960,896
  ushort* h     = (ushort*)(wsb + 106960896);     // 16384x512  ends 123,738,112
  ushort* mid   = (ushort*)(wsb + 123738112);     // 16384x2048 ends 190,846,976
  ushort* ffo   = (ushort*)(wsb + 190846976);     // 16384x512  ends 207,624,192

  const dim3 tb(64, 4);
  transpose_cast<<<dim3(8, 8),  tb, 0, stream>>>(Wq_w, wqkvt,              512, 512);
  transpose_cast<<<dim3(8, 8),  tb, 0, stream>>>(Wk_w, wqkvt + 512 * 512,  512, 512);
  transpose_cast<<<dim3(8, 8),  tb, 0, stream>>>(Wv_w, wqkvt + 1024 * 512, 512, 512);
  transpose_cast<<<dim3(8, 8),  tb, 0, stream>>>(Wu_w, wut, 512, 512);
  transpose_cast<<<dim3(32, 8), tb, 0, stream>>>(f1w, f1t, 512, 2048);
  transpose_cast<<<dim3(8, 32), tb, 0, stream>>>(f2w, f2t, 2048, 512);
  concat_bias<<<6, 256, 0, stream>>>(Wq_b, Wk_b, Wv_b, bqkv);

  // Fused QKV: qkv[16384][1536] = x @ Wqkv^T + b.
  gemm_sync_f32a<<<dim3(12, 128), 256, 0, stream>>>(x, wqkvt, bqkv, qkv, 1536, 512);

  // V^T per batch from strided v (qkv cols 1024..1535).
  for (int b = 0; b < 4; ++b)
    transpose_bf<<<dim3(8, 64), tb, 0, stream>>>(
        qkv + (size_t)b * 4096 * 1536 + 1024, vts + (size_t)b * 512 * 4096,
        4096, 512, 1536);

  // Flash attention (69,760 B dynamic LDS -> 2 blocks/CU; 512 blocks).
  hipFuncSetAttribute((const void*)flash_attn,
                      hipFuncAttributeMaxDynamicSharedMemorySize, 69760);
  flash_attn<<<512, 512, 69760, stream>>>(qkv, vts, attn);

  // Output projection + residual LN1.
  gemm_async<<<512, 256, 0, stream>>>(attn, wut, Wu_b, uni,
      512, 512, 512, 512, 2, 7, 1.f, 0);
  ln_res<<<4096, 256, 0, stream>>>(x, 1, uni, g1, b1, h, 0);

  // FFN + residual LN2 -> d_out (fp32).
  gemm_async<<<2048, 256, 0, stream>>>(h, f1t, f1b, mid,
      2048, 512, 512, 512, 4, 7, 1.f, GF_RELU);
  gemm_async<<<512, 256, 0, stream>>>(mid, f2t, f2bv, ffo,
      512, 2048, 2048, 2048, 2, 7, 1.f, 0);
  ln_res<<<4096, 256, 0, stream>>>(h, 0, ffo, g2, b2, d_out, 1);
}

// Round 4
// 670.797 us; speedup vs baseline: 2.2698x; 1.2653x over previous
//
#include <hip/hip_runtime.h>

#define AS1 __attribute__((address_space(1)))
#define AS3 __attribute__((address_space(3)))

typedef __attribute__((ext_vector_type(8))) short short8;
typedef __attribute__((ext_vector_type(4))) float floatx4;

__device__ __forceinline__ float b2f(ushort u) {
  union { unsigned int i; float f; } x; x.i = ((unsigned int)u) << 16; return x.f;
}
__device__ __forceinline__ ushort f2b(float f) {
  union { float f; unsigned int i; } x; x.f = f;
  unsigned int r = (x.i + 0x7fffu + ((x.i >> 16) & 1u)) >> 16;
  return (ushort)r;
}

#define GF_RELU 1

// ---------------------------------------------------------------------------
// Flash attention, producer-consumer wave specialization.
//
// History: v1 287us (64-row, 3-barrier lockstep), v2 292us (intra-block
// pipelining: no effect), v3 1145us (launch_bounds reg-cap spill), v4 490us
// (32-row tiles; occupancy stuck at 1 block/CU, overhead doubled).
// Lesson: 2 blocks/CU never materializes; lockstep phases serialize the
// ds-pipe, softmax VALU, and staging drain.
//
// v5: ONE 1024-thread block per CU (grid 256, 16 waves = 4 waves/SIMD
// guaranteed). Waves 0-7 (producers): Q persistent in regs, QK^T from
// double-buffered K in LDS, softmax, write P (double-buffered). Waves 8-15
// (consumers): stage K[it+1] via global_load_lds, V from L2 to regs,
// PV-MFMA from P[it-1]. ONE barrier per iteration; staging latency spans a
// full iteration of concurrent compute. Role branches are wave-uniform and
// top-level so qf[16] (QK-only) and oacc[4][4] (PV-only) overlay in the
// register file (both paths ~110 regs < 128 cap from launch_bounds(1024,1)).
// Row-sums: per-lane COLUMN partials accumulated per iter (no per-iter
// shuffles; sum over tiles commutes), one 4-shfl reduce + atomic at end.
// K staged via global_load_lds(16B), 16B-chunk XOR swizzle (keyed by row&7)
// on the SOURCE index. P via LDS (same swizzle) for the MFMA C->A turn.
// No max-subtraction (|s|<=~6).
// LDS: K 2x64KB + P 2x8KB + lsum = 147,712 B (single block, <=160KB).
// ---------------------------------------------------------------------------
__global__ __launch_bounds__(1024, 1) void flash_attn(
    const ushort* __restrict__ qkv,   // [4*4096][1536]: q cols 0.., k cols 512..
    const ushort* __restrict__ vts,   // [4][512][4096]  (V^T per batch)
    ushort* __restrict__ attn)        // [4*4096][512]
{
  extern __shared__ __align__(16) ushort smem[];
  ushort* Ks  = smem;                   // 2 x 64*512 elems (131072 B)
  ushort* P   = Ks + 2 * 64 * 512;      // 2 x 64*64 elems (16384 B)
  float* lsum = (float*)(P + 2 * 64 * 64); // 64 floats (256 B)

  const int tid  = threadIdx.x;
  const int w    = tid >> 6;            // 0..15
  const int lane = tid & 63;
  const int lo   = lane & 15;
  const int quad = lane >> 4;

  // batch -> XCD-pair mapping: b = (id&7)>>1 so same-batch blocks share L2.
  const int id = blockIdx.x;            // 0..255
  const int b  = (id & 7) >> 1;
  const int qt = ((id >> 3) << 1) | (id & 1);   // 0..63
  const size_t qrow0 = (size_t)b * 4096 + (size_t)qt * 64;

  const ushort* Qg = qkv + qrow0 * 1536;
  const ushort* Kg = qkv + (size_t)b * 4096 * 1536 + 512;
  const ushort* Vg = vts + (size_t)b * 512 * 4096;

  if (w < 8) {
    // ---------------- producer waves: QK^T + softmax -> P ----------------
    const int sr = w & 3;               // S row-block (16 rows)
    const int sc = w >> 2;              // S col-half (32 cols)

    short8 qf[16];                      // A[m=lo][k=t*32+quad*8+j]
#pragma unroll
    for (int t = 0; t < 16; ++t)
      qf[t] = *(const short8*)(Qg + (size_t)(sr * 16 + lo) * 1536 + t * 32 + quad * 8);

    float lpart[2][4] = {};             // per-lane COLUMN partials
    if (tid < 64) lsum[tid] = 0.f;
    __syncthreads();                    // B0: K[0] staged (by consumer waves)

    for (int it = 0; it < 65; ++it) {
      if (it < 64) {
        const ushort* Kc = Ks + (it & 1) * (64 * 512);
        floatx4 sacc[2] = {};
        __builtin_amdgcn_s_setprio(1);
#pragma unroll
        for (int t = 0; t < 16; ++t)
#pragma unroll
          for (int nt = 0; nt < 2; ++nt) {
            const int kpos = sc * 32 + nt * 16 + lo;
            const short8 kf = *(const short8*)(Kc + ((size_t)kpos * 64 + ((t * 4 + quad) ^ (kpos & 7))) * 8);
            sacc[nt] = __builtin_amdgcn_mfma_f32_16x16x32_bf16(qf[t], kf, sacc[nt], 0, 0, 0);
          }
        __builtin_amdgcn_s_setprio(0);

        ushort* Pc = P + (it & 1) * (64 * 64);
#pragma unroll
        for (int nt = 0; nt < 2; ++nt)
#pragma unroll
          for (int r = 0; r < 4; ++r) {
            const float e = __expf(sacc[nt][r] * 0.125f);
            lpart[nt][r] += e;          // no shuffle here: reduce once at end
            const int row = sr * 16 + quad * 4 + r;
            const int col = sc * 32 + nt * 16 + lo;
            Pc[((size_t)row * 8 + ((col >> 3) ^ (row & 7))) * 8 + (col & 7)] = f2b(e);
          }
      }
      __syncthreads();                  // B(it+1)
    }

    // Reduce column partials across the 16-lane group, one atomic per row.
#pragma unroll
    for (int nt = 0; nt < 2; ++nt)
#pragma unroll
      for (int r = 0; r < 4; ++r) {
        float s = lpart[nt][r];
        s += __shfl_xor(s, 1, 64);
        s += __shfl_xor(s, 2, 64);
        s += __shfl_xor(s, 4, 64);
        s += __shfl_xor(s, 8, 64);
        if (lo == 0) atomicAdd(&lsum[sr * 16 + quad * 4 + r], s);
      }
    __syncthreads();                    // B66: lsum final
  } else {
    // ------------- consumer waves: K staging + PV accumulation -------------
    const int wp = w - 8;               // 0..7: O cols wp*64..+64
    const int t2 = tid - 512;           // 0..511

    // Prologue: stage K[0] into buffer 0.
#pragma unroll
    for (int k = 0; k < 8; ++k) {
      const int s = t2 + k * 512;
      const int pos = s >> 6, sl = s & 63;
      const ushort* src = Kg + (size_t)pos * 1536 + ((sl ^ (pos & 7)) << 3);
      __builtin_amdgcn_global_load_lds((const AS1 void*)src, (AS3 void*)(Ks + s * 8), 16, 0, 0);
    }
    floatx4 oacc[4][4] = {};            // O rows 64 (mt), cols wp*64+nt*16+lo
    __syncthreads();                    // B0: drain -> K[0] visible

    for (int it = 0; it < 65; ++it) {
      if (it < 63) {                    // stage K[it+1] (drained at this iter's barrier)
        const int jn = (it + 1) * 64;
        ushort* Kn = Ks + ((it + 1) & 1) * (64 * 512);
#pragma unroll
        for (int k = 0; k < 8; ++k) {
          const int s = t2 + k * 512;
          const int pos = s >> 6, sl = s & 63;
          const ushort* src = Kg + (size_t)(jn + pos) * 1536 + ((sl ^ (pos & 7)) << 3);
          __builtin_amdgcn_global_load_lds((const AS1 void*)src, (AS3 void*)(Kn + s * 8), 16, 0, 0);
        }
      }
      if (it >= 1) {                    // consume P[it-1], V[it-1]
        const int jp = (it - 1) * 64;
        const ushort* Pc = P + ((it - 1) & 1) * (64 * 64);
#pragma unroll
        for (int kc = 0; kc < 2; ++kc) {
          short8 vf[4], pf[4];
#pragma unroll
          for (int nt = 0; nt < 4; ++nt) {
            const int dc = wp * 64 + nt * 16 + lo;
            vf[nt] = *(const short8*)(Vg + (size_t)dc * 4096 + jp + ((kc * 4 + quad) << 3));
          }
#pragma unroll
          for (int mt = 0; mt < 4; ++mt) {
            const int row = mt * 16 + lo;
            pf[mt] = *(const short8*)(Pc + ((size_t)row * 8 + ((kc * 4 + quad) ^ (row & 7))) * 8);
          }
          __builtin_amdgcn_s_setprio(1);
#pragma unroll
          for (int mt = 0; mt < 4; ++mt)
#pragma unroll
            for (int nt = 0; nt < 4; ++nt)
              oacc[mt][nt] = __builtin_amdgcn_mfma_f32_16x16x32_bf16(pf[mt], vf[nt], oacc[mt][nt], 0, 0, 0);
          __builtin_amdgcn_s_setprio(0);
        }
      }
      __syncthreads();                  // B(it+1)
    }
    __syncthreads();                    // B66: lsum final

#pragma unroll
    for (int mt = 0; mt < 4; ++mt)
#pragma unroll
      for (int r = 0; r < 4; ++r) {
        const int row = mt * 16 + quad * 4 + r;
        const float inv = 1.f / lsum[row];
#pragma unroll
        for (int nt = 0; nt < 4; ++nt)
          attn[(qrow0 + row) * 512 + wp * 64 + nt * 16 + lo] = f2b(oacc[mt][nt][r] * inv);
      }
  }
}

// ---------------------------------------------------------------------------
// Async NT GEMM, flat grid with XCD swizzle (Wu / FF1 / FF2).
// ---------------------------------------------------------------------------
__global__ __launch_bounds__(256) void gemm_async(
    const ushort* __restrict__ A, const ushort* __restrict__ Bt,
    const float* __restrict__ bias, ushort* __restrict__ C,
    int N, int K, int lda, int ldb,
    int lg_gx, int lg_gy, float scale, int flags)
{
  __shared__ __align__(16) ushort As[128 * 32];
  __shared__ __align__(16) ushort Bs[128 * 32];

  const int id = blockIdx.x;
  const int r8 = id & 7;
  const int s  = id >> 3;
  const int bx = s & ((1 << lg_gx) - 1);
  const int j  = r8 + ((s >> lg_gx) << 3);
  const int by = j & ((1 << lg_gy) - 1);

  const int tid  = threadIdx.x;
  const int w    = tid >> 6;
  const int lane = tid & 63;
  const int lo   = lane & 15;
  const int quad = lane >> 4;
  const int m0   = by * 128;
  const int n0   = bx * 128;
  const int wm   = (w & 1) * 64;
  const int wn   = (w >> 1) * 64;

  const int i0 = tid, i1 = tid + 256;
  const ushort* ga0 = A  + (size_t)(m0 + (i0 >> 2)) * lda + ((i0 & 3) << 3);
  const ushort* ga1 = A  + (size_t)(m0 + (i1 >> 2)) * lda + ((i1 & 3) << 3);
  const ushort* gb0 = Bt + (size_t)(n0 + (i0 >> 2)) * ldb + ((i0 & 3) << 3);
  const ushort* gb1 = Bt + (size_t)(n0 + (i1 >> 2)) * ldb + ((i1 & 3) << 3);

  floatx4 acc[4][4] = {};

  for (int k0 = 0; k0 < K; k0 += 32) {
    __syncthreads();
    __builtin_amdgcn_global_load_lds((const AS1 void*)(ga0 + k0), (AS3 void*)(As + i0 * 8), 16, 0, 0);
    __builtin_amdgcn_global_load_lds((const AS1 void*)(ga1 + k0), (AS3 void*)(As + i1 * 8), 16, 0, 0);
    __builtin_amdgcn_global_load_lds((const AS1 void*)(gb0 + k0), (AS3 void*)(Bs + i0 * 8), 16, 0, 0);
    __builtin_amdgcn_global_load_lds((const AS1 void*)(gb1 + k0), (AS3 void*)(Bs + i1 * 8), 16, 0, 0);
    __syncthreads();

    short8 af[4], bf[4];
#pragma unroll
    for (int t = 0; t < 4; ++t) {
      af[t] = *(const short8*)(As + (wm + t * 16 + lo) * 32 + quad * 8);
      bf[t] = *(const short8*)(Bs + (wn + t * 16 + lo) * 32 + quad * 8);
    }
#pragma unroll
    for (int mt = 0; mt < 4; ++mt)
#pragma unroll
      for (int nt = 0; nt < 4; ++nt)
        acc[mt][nt] = __builtin_amdgcn_mfma_f32_16x16x32_bf16(af[mt], bf[nt], acc[mt][nt], 0, 0, 0);
  }

#pragma unroll
  for (int mt = 0; mt < 4; ++mt)
#pragma unroll
    for (int nt = 0; nt < 4; ++nt)
#pragma unroll
      for (int r = 0; r < 4; ++r) {
        int row = m0 + wm + mt * 16 + quad * 4 + r;
        int col = n0 + wn + nt * 16 + lo;
        float v = acc[mt][nt][r] * scale;
        if (bias) v += bias[col];
        if (flags & GF_RELU) v = fmaxf(v, 0.f);
        C[(size_t)row * N + col] = f2b(v);
      }
}

// ---------------------------------------------------------------------------
// Sync NT GEMM with fp32 A (cast in staging) — fused QKV projection.
// ---------------------------------------------------------------------------
__global__ __launch_bounds__(256) void gemm_sync_f32a(
    const float* __restrict__ Af, const ushort* __restrict__ Bt,
    const float* __restrict__ bias, ushort* __restrict__ C,
    int N, int K)
{
  __shared__ __align__(16) ushort As[128 * 32];
  __shared__ __align__(16) ushort Bs[128 * 32];

  const int tid  = threadIdx.x;
  const int w    = tid >> 6;
  const int lane = tid & 63;
  const int lo   = lane & 15;
  const int quad = lane >> 4;
  const int m0   = blockIdx.y * 128;
  const int n0   = blockIdx.x * 128;
  const int wm   = (w & 1) * 64;
  const int wn   = (w >> 1) * 64;

  const int i0 = tid, i1 = tid + 256;
  const size_t aoff0 = (size_t)(m0 + (i0 >> 2)) * K + ((i0 & 3) << 3);
  const size_t aoff1 = (size_t)(m0 + (i1 >> 2)) * K + ((i1 & 3) << 3);
  const size_t boff0 = (size_t)(n0 + (i0 >> 2)) * K + ((i0 & 3) << 3);
  const size_t boff1 = (size_t)(n0 + (i1 >> 2)) * K + ((i1 & 3) << 3);

  floatx4 acc[4][4] = {};

  for (int k0 = 0; k0 < K; k0 += 32) {
    short8 va0, va1;
    const float4 a00 = *(const float4*)(Af + aoff0 + k0);
    const float4 a01 = *(const float4*)(Af + aoff0 + k0 + 4);
    const float4 a10 = *(const float4*)(Af + aoff1 + k0);
    const float4 a11 = *(const float4*)(Af + aoff1 + k0 + 4);
    va0[0] = (short)f2b(a00.x); va0[1] = (short)f2b(a00.y);
    va0[2] = (short)f2b(a00.z); va0[3] = (short)f2b(a00.w);
    va0[4] = (short)f2b(a01.x); va0[5] = (short)f2b(a01.y);
    va0[6] = (short)f2b(a01.z); va0[7] = (short)f2b(a01.w);
    va1[0] = (short)f2b(a10.x); va1[1] = (short)f2b(a10.y);
    va1[2] = (short)f2b(a10.z); va1[3] = (short)f2b(a10.w);
    va1[4] = (short)f2b(a11.x); va1[5] = (short)f2b(a11.y);
    va1[6] = (short)f2b(a11.z); va1[7] = (short)f2b(a11.w);
    const short8 vb0 = *(const short8*)(Bt + boff0 + k0);
    const short8 vb1 = *(const short8*)(Bt + boff1 + k0);
    __syncthreads();
    *(short8*)(As + i0 * 8) = va0;
    *(short8*)(As + i1 * 8) = va1;
    *(short8*)(Bs + i0 * 8) = vb0;
    *(short8*)(Bs + i1 * 8) = vb1;
    __syncthreads();

    short8 af[4], bf[4];
#pragma unroll
    for (int t = 0; t < 4; ++t) {
      af[t] = *(const short8*)(As + (wm + t * 16 + lo) * 32 + quad * 8);
      bf[t] = *(const short8*)(Bs + (wn + t * 16 + lo) * 32 + quad * 8);
    }
#pragma unroll
    for (int mt = 0; mt < 4; ++mt)
#pragma unroll
      for (int nt = 0; nt < 4; ++nt)
        acc[mt][nt] = __builtin_amdgcn_mfma_f32_16x16x32_bf16(af[mt], bf[nt], acc[mt][nt], 0, 0, 0);
  }

#pragma unroll
  for (int mt = 0; mt < 4; ++mt)
#pragma unroll
    for (int nt = 0; nt < 4; ++nt)
#pragma unroll
      for (int r = 0; r < 4; ++r) {
        int row = m0 + wm + mt * 16 + quad * 4 + r;
        int col = n0 + wn + nt * 16 + lo;
        C[(size_t)row * N + col] = f2b(acc[mt][nt][r] + bias[col]);
      }
}

// ---------------------------------------------------------------------------
__global__ void transpose_cast(const float* __restrict__ in, ushort* __restrict__ out,
                               int R, int C)
{
  __shared__ ushort t[64][65];
  const int r0 = blockIdx.y * 64, c0 = blockIdx.x * 64;
  const int tx = threadIdx.x, ty = threadIdx.y;
  for (int i = ty; i < 64; i += 4)
    t[i][tx] = f2b(in[(size_t)(r0 + i) * C + c0 + tx]);
  __syncthreads();
  for (int i = ty; i < 64; i += 4)
    out[(size_t)(c0 + i) * R + r0 + tx] = t[tx][i];
}

__global__ void transpose_bf(const ushort* __restrict__ in, ushort* __restrict__ out,
                             int R, int C, int ldin)
{
  __shared__ ushort t[64][65];
  const int r0 = blockIdx.y * 64, c0 = blockIdx.x * 64;
  const int tx = threadIdx.x, ty = threadIdx.y;
  for (int i = ty; i < 64; i += 4)
    t[i][tx] = in[(size_t)(r0 + i) * ldin + c0 + tx];
  __syncthreads();
  for (int i = ty; i < 64; i += 4)
    out[(size_t)(c0 + i) * R + r0 + tx] = t[tx][i];
}

__global__ void concat_bias(const float* __restrict__ a, const float* __restrict__ b,
                            const float* __restrict__ c, float* __restrict__ o)
{
  const int i = blockIdx.x * 256 + threadIdx.x;
  o[i] = (i < 512) ? a[i] : ((i < 1024) ? b[i - 512] : c[i - 1024]);
}

// ---------------------------------------------------------------------------
// out = LayerNorm(X + Y) * g + b. X fp32/bf16, Y bf16, out fp32/bf16.
// ---------------------------------------------------------------------------
__global__ __launch_bounds__(256) void ln_res(
    const void* __restrict__ Xv, int x_f32, const ushort* __restrict__ Y,
    const float* __restrict__ g, const float* __restrict__ b,
    void* __restrict__ outv, int o_f32)
{
  const int w = threadIdx.x >> 6, lane = threadIdx.x & 63;
  const size_t row = (size_t)blockIdx.x * 4 + w;
  const size_t base = row * 512 + lane * 8;

  float v[8];
  if (x_f32) {
    const float* X = (const float*)Xv + base;
    const float4 x0 = *(const float4*)(X), x1 = *(const float4*)(X + 4);
    v[0] = x0.x; v[1] = x0.y; v[2] = x0.z; v[3] = x0.w;
    v[4] = x1.x; v[5] = x1.y; v[6] = x1.z; v[7] = x1.w;
  } else {
    const short8 xv = *(const short8*)((const ushort*)Xv + base);
#pragma unroll
    for (int j = 0; j < 8; ++j) v[j] = b2f((ushort)xv[j]);
  }
  const short8 yv = *(const short8*)(Y + base);
  float s = 0.f, sq = 0.f;
#pragma unroll
  for (int j = 0; j < 8; ++j) {
    v[j] += b2f((ushort)yv[j]);
    s += v[j]; sq += v[j] * v[j];
  }
  for (int m = 1; m < 64; m <<= 1) {
    s  += __shfl_xor(s,  m, 64);
    sq += __shfl_xor(sq, m, 64);
  }
  const float mean = s * (1.f / 512.f);
  const float var  = sq * (1.f / 512.f) - mean * mean;
  const float rstd = rsqrtf(fmaxf(var, 0.f) + 1e-5f);

  const float4 g0 = *(const float4*)(g + lane * 8);
  const float4 g1 = *(const float4*)(g + lane * 8 + 4);
  const float4 b0 = *(const float4*)(b + lane * 8);
  const float4 b1 = *(const float4*)(b + lane * 8 + 4);
  const float gg[8] = {g0.x, g0.y, g0.z, g0.w, g1.x, g1.y, g1.z, g1.w};
  const float bb[8] = {b0.x, b0.y, b0.z, b0.w, b1.x, b1.y, b1.z, b1.w};

  if (o_f32) {
    float* o = (float*)outv + base;
#pragma unroll
    for (int j = 0; j < 8; ++j) o[j] = (v[j] - mean) * rstd * gg[j] + bb[j];
  } else {
    ushort* o = (ushort*)outv + base;
    short8 ov;
#pragma unroll
    for (int j = 0; j < 8; ++j) ov[j] = (short)f2b((v[j] - mean) * rstd * gg[j] + bb[j]);
    *(short8*)o = ov;
  }
}

// ---------------------------------------------------------------------------
extern "C" void kernel_launch(void* const* d_in, const int* in_sizes, int n_in,
                              void* d_out, int out_size, void* d_ws, size_t ws_size,
                              hipStream_t stream)
{
  const float* x    = (const float*)d_in[0];
  const float* Wq_w = (const float*)d_in[1];
  const float* Wq_b = (const float*)d_in[2];
  const float* Wk_w = (const float*)d_in[3];
  const float* Wk_b = (const float*)d_in[4];
  const float* Wv_w = (const float*)d_in[5];
  const float* Wv_b = (const float*)d_in[6];
  const float* Wu_w = (const float*)d_in[7];
  const float* Wu_b = (const float*)d_in[8];
  const float* g1   = (const float*)d_in[9];
  const float* b1   = (const float*)d_in[10];
  const float* f1w  = (const float*)d_in[11];
  const float* f1b  = (const float*)d_in[12];
  const float* f2w  = (const float*)d_in[13];
  const float* f2bv = (const float*)d_in[14];
  const float* g2   = (const float*)d_in[15];
  const float* b2   = (const float*)d_in[16];

  // Workspace (byte offsets; peak 207.6 MB <= 224.4 MB known floor).
  char* wsb = (char*)d_ws;
  ushort* wqkvt = (ushort*)(wsb + 0);             // 1536x512   ends   1,572,864
  ushort* wut   = (ushort*)(wsb + 1572864);       //  512x512   ends   2,097,152
  ushort* f1t   = (ushort*)(wsb + 2097152);       // 2048x512   ends   4,194,304
  ushort* f2t   = (ushort*)(wsb + 4194304);       //  512x2048  ends   6,291,456
  float*  bqkv  = (float*) (wsb + 6291456);       // 1536 f32   ends   6,297,600
  ushort* qkv   = (ushort*)(wsb + 6297600);       // 16384x1536 ends  56,629,248
  ushort* vts   = (ushort*)(wsb + 56629248);      // 4x512x4096 ends  73,406,464
  ushort* attn  = (ushort*)(wsb + 73406464);      // 16384x512  ends  90,183,680
  ushort* uni   = (ushort*)(wsb + 90183680);      // 16384x512  ends 106,960,896
  ushort* h     = (ushort*)(wsb + 106960896);     // 16384x512  ends 123,738,112
  ushort* mid   = (ushort*)(wsb + 123738112);     // 16384x2048 ends 190,846,976
  ushort* ffo   = (ushort*)(wsb + 190846976);     // 16384x512  ends 207,624,192

  const dim3 tb(64, 4);
  transpose_cast<<<dim3(8, 8),  tb, 0, stream>>>(Wq_w, wqkvt,              512, 512);
  transpose_cast<<<dim3(8, 8),  tb, 0, stream>>>(Wk_w, wqkvt + 512 * 512,  512, 512);
  transpose_cast<<<dim3(8, 8),  tb, 0, stream>>>(Wv_w, wqkvt + 1024 * 512, 512, 512);
  transpose_cast<<<dim3(8, 8),  tb, 0, stream>>>(Wu_w, wut, 512, 512);
  transpose_cast<<<dim3(32, 8), tb, 0, stream>>>(f1w, f1t, 512, 2048);
  transpose_cast<<<dim3(8, 32), tb, 0, stream>>>(f2w, f2t, 2048, 512);
  concat_bias<<<6, 256, 0, stream>>>(Wq_b, Wk_b, Wv_b, bqkv);

  // Fused QKV: qkv[16384][1536] = x @ Wqkv^T + b.
  gemm_sync_f32a<<<dim3(12, 128), 256, 0, stream>>>(x, wqkvt, bqkv, qkv, 1536, 512);

  // V^T per batch from strided v (qkv cols 1024..1535).
  for (int b = 0; b < 4; ++b)
    transpose_bf<<<dim3(8, 64), tb, 0, stream>>>(
        qkv + (size_t)b * 4096 * 1536 + 1024, vts + (size_t)b * 512 * 4096,
        4096, 512, 1536);

  // Flash attention: 256 blocks x 1024 thr, 147,712 B dynamic LDS.
  hipFuncSetAttribute((const void*)flash_attn,
                      hipFuncAttributeMaxDynamicSharedMemorySize, 147712);
  flash_attn<<<256, 1024, 147712, stream>>>(qkv, vts, attn);

  // Output projection + residual LN1.
  gemm_async<<<512, 256, 0, stream>>>(attn, wut, Wu_b, uni,
      512, 512, 512, 512, 2, 7, 1.f, 0);
  ln_res<<<4096, 256, 0, stream>>>(x, 1, uni, g1, b1, h, 0);

  // FFN + residual LN2 -> d_out (fp32).
  gemm_async<<<2048, 256, 0, stream>>>(h, f1t, f1b, mid,
      2048, 512, 512, 512, 4, 7, 1.f, GF_RELU);
  gemm_async<<<512, 256, 0, stream>>>(mid, f2t, f2bv, ffo,
      512, 2048, 2048, 2048, 2, 7, 1.f, 0);
  ln_res<<<4096, 256, 0, stream>>>(h, 0, ffo, g2, b2, d_out, 1);
}

// Round 5
// 638.259 us; speedup vs baseline: 2.3855x; 1.0510x over previous
//
#include <hip/hip_runtime.h>

#define AS1 __attribute__((address_space(1)))
#define AS3 __attribute__((address_space(3)))

typedef __attribute__((ext_vector_type(8))) short short8;
typedef __attribute__((ext_vector_type(4))) float floatx4;

__device__ __forceinline__ float b2f(ushort u) {
  union { unsigned int i; float f; } x; x.i = ((unsigned int)u) << 16; return x.f;
}
__device__ __forceinline__ ushort f2b(float f) {
  union { float f; unsigned int i; } x; x.f = f;
  unsigned int r = (x.i + 0x7fffu + ((x.i >> 16) & 1u)) >> 16;
  return (ushort)r;
}

#define GF_RELU 1

// ---------------------------------------------------------------------------
// Attention = 3 passes of plain GEMM-shaped work (v6).
//
// History: fused flash v1 287us / v2 292us / v3 1145us (reg-cap spill) /
// v4 490us / v5 306us (producer-consumer, 46% occupancy). Three structurally
// different schedules all pinned at ~290-306us, MfmaUtil ~19-20%: the fused
// 64-iter barrier'd K-stream has a ~2x stall multiplier none of them removed
// (and SQ_LDS_BANK_CONFLICT saturates at 256*2^16 -> conflicts invisible).
// D=512 un-split attention is just two dense GEMMs (68.7 GF each), so:
//   A: P = exp(QK^T/8) bf16 -> 134MB workspace (L3-resident)
//   B: rowsum[i] = sum_j P[i][j]   (no atomics, one wave/row)
//   C: attn = (P @ V) / rowsum     (NT GEMM vs vts, K=4096)
// All three reuse the harness-proven gemm_async skeleton verbatim.
// ---------------------------------------------------------------------------

// Pass A: P = exp((Q.K^T)/8). A=Q (qkv cols 0..511), Bt=K (qkv cols 512..1023),
// both lda/ldb=1536. Per batch: M=N=4096, K=512. Grid 4096 = 4 batches x 32x32.
__global__ __launch_bounds__(256) void gemm_qk_exp(
    const ushort* __restrict__ qkv, ushort* __restrict__ P)
{
  __shared__ __align__(16) ushort As[128 * 32];
  __shared__ __align__(16) ushort Bs[128 * 32];

  const int id = blockIdx.x;
  const int b  = id >> 10;            // batch
  const int t  = id & 1023;
  const int r8 = t & 7;               // XCD swizzle
  const int s2 = t >> 3;
  const int bx = s2 & 31;
  const int by = r8 + ((s2 >> 5) << 3);

  const ushort* A  = qkv + (size_t)b * 4096 * 1536;        // Q rows
  const ushort* Bt = qkv + (size_t)b * 4096 * 1536 + 512;  // K rows
  ushort* C = P + (size_t)b * 4096 * 4096;

  const int tid  = threadIdx.x;
  const int w    = tid >> 6;
  const int lane = tid & 63;
  const int lo   = lane & 15;
  const int quad = lane >> 4;
  const int m0   = by * 128;
  const int n0   = bx * 128;
  const int wm   = (w & 1) * 64;
  const int wn   = (w >> 1) * 64;

  const int i0 = tid, i1 = tid + 256;
  const ushort* ga0 = A  + (size_t)(m0 + (i0 >> 2)) * 1536 + ((i0 & 3) << 3);
  const ushort* ga1 = A  + (size_t)(m0 + (i1 >> 2)) * 1536 + ((i1 & 3) << 3);
  const ushort* gb0 = Bt + (size_t)(n0 + (i0 >> 2)) * 1536 + ((i0 & 3) << 3);
  const ushort* gb1 = Bt + (size_t)(n0 + (i1 >> 2)) * 1536 + ((i1 & 3) << 3);

  floatx4 acc[4][4] = {};

  for (int k0 = 0; k0 < 512; k0 += 32) {
    __syncthreads();
    __builtin_amdgcn_global_load_lds((const AS1 void*)(ga0 + k0), (AS3 void*)(As + i0 * 8), 16, 0, 0);
    __builtin_amdgcn_global_load_lds((const AS1 void*)(ga1 + k0), (AS3 void*)(As + i1 * 8), 16, 0, 0);
    __builtin_amdgcn_global_load_lds((const AS1 void*)(gb0 + k0), (AS3 void*)(Bs + i0 * 8), 16, 0, 0);
    __builtin_amdgcn_global_load_lds((const AS1 void*)(gb1 + k0), (AS3 void*)(Bs + i1 * 8), 16, 0, 0);
    __syncthreads();

    short8 af[4], bf[4];
#pragma unroll
    for (int tt = 0; tt < 4; ++tt) {
      af[tt] = *(const short8*)(As + (wm + tt * 16 + lo) * 32 + quad * 8);
      bf[tt] = *(const short8*)(Bs + (wn + tt * 16 + lo) * 32 + quad * 8);
    }
#pragma unroll
    for (int mt = 0; mt < 4; ++mt)
#pragma unroll
      for (int nt = 0; nt < 4; ++nt)
        acc[mt][nt] = __builtin_amdgcn_mfma_f32_16x16x32_bf16(af[mt], bf[nt], acc[mt][nt], 0, 0, 0);
  }

#pragma unroll
  for (int mt = 0; mt < 4; ++mt)
#pragma unroll
    for (int nt = 0; nt < 4; ++nt)
#pragma unroll
      for (int r = 0; r < 4; ++r) {
        const int row = m0 + wm + mt * 16 + quad * 4 + r;
        const int col = n0 + wn + nt * 16 + lo;
        C[(size_t)row * 4096 + col] = f2b(__expf(acc[mt][nt][r] * 0.125f));
      }
}

// rowsum[i] = sum_j P[i][j]. One wave per row; pure coalesced short8 reads.
__global__ __launch_bounds__(256) void row_sums(
    const ushort* __restrict__ P, float* __restrict__ rs)
{
  const int w = threadIdx.x >> 6, lane = threadIdx.x & 63;
  const size_t row = (size_t)blockIdx.x * 4 + w;  // 0..16383
  const ushort* p = P + row * 4096;
  float s = 0.f;
#pragma unroll
  for (int it = 0; it < 8; ++it) {
    const short8 v = *(const short8*)(p + it * 512 + lane * 8);
#pragma unroll
    for (int j = 0; j < 8; ++j) s += b2f((ushort)v[j]);
  }
  for (int m = 1; m < 64; m <<= 1) s += __shfl_xor(s, m, 64);
  if (lane == 0) rs[row] = s;
}

// Pass C: attn = (P @ V) / rowsum. NT GEMM: A=P (lda 4096), Bt=vts (ldb 4096),
// per batch M=4096, N=512, K=4096. Grid 512 = 4 batches x 32x4.
__global__ __launch_bounds__(256) void gemm_pv_norm(
    const ushort* __restrict__ P, const ushort* __restrict__ vts,
    const float* __restrict__ rs, ushort* __restrict__ attn)
{
  __shared__ __align__(16) ushort As[128 * 32];
  __shared__ __align__(16) ushort Bs[128 * 32];

  const int id = blockIdx.x;
  const int b  = id >> 7;
  const int t  = id & 127;
  const int bx = t & 3;
  const int by = t >> 2;

  const ushort* A  = P   + (size_t)b * 4096 * 4096;
  const ushort* Bt = vts + (size_t)b * 512 * 4096;

  const int tid  = threadIdx.x;
  const int w    = tid >> 6;
  const int lane = tid & 63;
  const int lo   = lane & 15;
  const int quad = lane >> 4;
  const int m0   = by * 128;
  const int n0   = bx * 128;
  const int wm   = (w & 1) * 64;
  const int wn   = (w >> 1) * 64;

  const int i0 = tid, i1 = tid + 256;
  const ushort* ga0 = A  + (size_t)(m0 + (i0 >> 2)) * 4096 + ((i0 & 3) << 3);
  const ushort* ga1 = A  + (size_t)(m0 + (i1 >> 2)) * 4096 + ((i1 & 3) << 3);
  const ushort* gb0 = Bt + (size_t)(n0 + (i0 >> 2)) * 4096 + ((i0 & 3) << 3);
  const ushort* gb1 = Bt + (size_t)(n0 + (i1 >> 2)) * 4096 + ((i1 & 3) << 3);

  floatx4 acc[4][4] = {};

  for (int k0 = 0; k0 < 4096; k0 += 32) {
    __syncthreads();
    __builtin_amdgcn_global_load_lds((const AS1 void*)(ga0 + k0), (AS3 void*)(As + i0 * 8), 16, 0, 0);
    __builtin_amdgcn_global_load_lds((const AS1 void*)(ga1 + k0), (AS3 void*)(As + i1 * 8), 16, 0, 0);
    __builtin_amdgcn_global_load_lds((const AS1 void*)(gb0 + k0), (AS3 void*)(Bs + i0 * 8), 16, 0, 0);
    __builtin_amdgcn_global_load_lds((const AS1 void*)(gb1 + k0), (AS3 void*)(Bs + i1 * 8), 16, 0, 0);
    __syncthreads();

    short8 af[4], bf[4];
#pragma unroll
    for (int tt = 0; tt < 4; ++tt) {
      af[tt] = *(const short8*)(As + (wm + tt * 16 + lo) * 32 + quad * 8);
      bf[tt] = *(const short8*)(Bs + (wn + tt * 16 + lo) * 32 + quad * 8);
    }
#pragma unroll
    for (int mt = 0; mt < 4; ++mt)
#pragma unroll
      for (int nt = 0; nt < 4; ++nt)
        acc[mt][nt] = __builtin_amdgcn_mfma_f32_16x16x32_bf16(af[mt], bf[nt], acc[mt][nt], 0, 0, 0);
  }

#pragma unroll
  for (int mt = 0; mt < 4; ++mt)
#pragma unroll
    for (int r = 0; r < 4; ++r) {
      const int row = m0 + wm + mt * 16 + quad * 4 + r;
      const float inv = 1.f / rs[(size_t)b * 4096 + row];
#pragma unroll
      for (int nt = 0; nt < 4; ++nt) {
        const int col = n0 + wn + nt * 16 + lo;
        attn[((size_t)b * 4096 + row) * 512 + col] = f2b(acc[mt][nt][r] * inv);
      }
    }
}

// ---------------------------------------------------------------------------
// Async NT GEMM, flat grid with XCD swizzle (Wu / FF1 / FF2).
// ---------------------------------------------------------------------------
__global__ __launch_bounds__(256) void gemm_async(
    const ushort* __restrict__ A, const ushort* __restrict__ Bt,
    const float* __restrict__ bias, ushort* __restrict__ C,
    int N, int K, int lda, int ldb,
    int lg_gx, int lg_gy, float scale, int flags)
{
  __shared__ __align__(16) ushort As[128 * 32];
  __shared__ __align__(16) ushort Bs[128 * 32];

  const int id = blockIdx.x;
  const int r8 = id & 7;
  const int s  = id >> 3;
  const int bx = s & ((1 << lg_gx) - 1);
  const int j  = r8 + ((s >> lg_gx) << 3);
  const int by = j & ((1 << lg_gy) - 1);

  const int tid  = threadIdx.x;
  const int w    = tid >> 6;
  const int lane = tid & 63;
  const int lo   = lane & 15;
  const int quad = lane >> 4;
  const int m0   = by * 128;
  const int n0   = bx * 128;
  const int wm   = (w & 1) * 64;
  const int wn   = (w >> 1) * 64;

  const int i0 = tid, i1 = tid + 256;
  const ushort* ga0 = A  + (size_t)(m0 + (i0 >> 2)) * lda + ((i0 & 3) << 3);
  const ushort* ga1 = A  + (size_t)(m0 + (i1 >> 2)) * lda + ((i1 & 3) << 3);
  const ushort* gb0 = Bt + (size_t)(n0 + (i0 >> 2)) * ldb + ((i0 & 3) << 3);
  const ushort* gb1 = Bt + (size_t)(n0 + (i1 >> 2)) * ldb + ((i1 & 3) << 3);

  floatx4 acc[4][4] = {};

  for (int k0 = 0; k0 < K; k0 += 32) {
    __syncthreads();
    __builtin_amdgcn_global_load_lds((const AS1 void*)(ga0 + k0), (AS3 void*)(As + i0 * 8), 16, 0, 0);
    __builtin_amdgcn_global_load_lds((const AS1 void*)(ga1 + k0), (AS3 void*)(As + i1 * 8), 16, 0, 0);
    __builtin_amdgcn_global_load_lds((const AS1 void*)(gb0 + k0), (AS3 void*)(Bs + i0 * 8), 16, 0, 0);
    __builtin_amdgcn_global_load_lds((const AS1 void*)(gb1 + k0), (AS3 void*)(Bs + i1 * 8), 16, 0, 0);
    __syncthreads();

    short8 af[4], bf[4];
#pragma unroll
    for (int t = 0; t < 4; ++t) {
      af[t] = *(const short8*)(As + (wm + t * 16 + lo) * 32 + quad * 8);
      bf[t] = *(const short8*)(Bs + (wn + t * 16 + lo) * 32 + quad * 8);
    }
#pragma unroll
    for (int mt = 0; mt < 4; ++mt)
#pragma unroll
      for (int nt = 0; nt < 4; ++nt)
        acc[mt][nt] = __builtin_amdgcn_mfma_f32_16x16x32_bf16(af[mt], bf[nt], acc[mt][nt], 0, 0, 0);
  }

#pragma unroll
  for (int mt = 0; mt < 4; ++mt)
#pragma unroll
    for (int nt = 0; nt < 4; ++nt)
#pragma unroll
      for (int r = 0; r < 4; ++r) {
        int row = m0 + wm + mt * 16 + quad * 4 + r;
        int col = n0 + wn + nt * 16 + lo;
        float v = acc[mt][nt][r] * scale;
        if (bias) v += bias[col];
        if (flags & GF_RELU) v = fmaxf(v, 0.f);
        C[(size_t)row * N + col] = f2b(v);
      }
}

// ---------------------------------------------------------------------------
// Sync NT GEMM with fp32 A (cast in staging) — fused QKV projection.
// ---------------------------------------------------------------------------
__global__ __launch_bounds__(256) void gemm_sync_f32a(
    const float* __restrict__ Af, const ushort* __restrict__ Bt,
    const float* __restrict__ bias, ushort* __restrict__ C,
    int N, int K)
{
  __shared__ __align__(16) ushort As[128 * 32];
  __shared__ __align__(16) ushort Bs[128 * 32];

  const int tid  = threadIdx.x;
  const int w    = tid >> 6;
  const int lane = tid & 63;
  const int lo   = lane & 15;
  const int quad = lane >> 4;
  const int m0   = blockIdx.y * 128;
  const int n0   = blockIdx.x * 128;
  const int wm   = (w & 1) * 64;
  const int wn   = (w >> 1) * 64;

  const int i0 = tid, i1 = tid + 256;
  const size_t aoff0 = (size_t)(m0 + (i0 >> 2)) * K + ((i0 & 3) << 3);
  const size_t aoff1 = (size_t)(m0 + (i1 >> 2)) * K + ((i1 & 3) << 3);
  const size_t boff0 = (size_t)(n0 + (i0 >> 2)) * K + ((i0 & 3) << 3);
  const size_t boff1 = (size_t)(n0 + (i1 >> 2)) * K + ((i1 & 3) << 3);

  floatx4 acc[4][4] = {};

  for (int k0 = 0; k0 < K; k0 += 32) {
    short8 va0, va1;
    const float4 a00 = *(const float4*)(Af + aoff0 + k0);
    const float4 a01 = *(const float4*)(Af + aoff0 + k0 + 4);
    const float4 a10 = *(const float4*)(Af + aoff1 + k0);
    const float4 a11 = *(const float4*)(Af + aoff1 + k0 + 4);
    va0[0] = (short)f2b(a00.x); va0[1] = (short)f2b(a00.y);
    va0[2] = (short)f2b(a00.z); va0[3] = (short)f2b(a00.w);
    va0[4] = (short)f2b(a01.x); va0[5] = (short)f2b(a01.y);
    va0[6] = (short)f2b(a01.z); va0[7] = (short)f2b(a01.w);
    va1[0] = (short)f2b(a10.x); va1[1] = (short)f2b(a10.y);
    va1[2] = (short)f2b(a10.z); va1[3] = (short)f2b(a10.w);
    va1[4] = (short)f2b(a11.x); va1[5] = (short)f2b(a11.y);
    va1[6] = (short)f2b(a11.z); va1[7] = (short)f2b(a11.w);
    const short8 vb0 = *(const short8*)(Bt + boff0 + k0);
    const short8 vb1 = *(const short8*)(Bt + boff1 + k0);
    __syncthreads();
    *(short8*)(As + i0 * 8) = va0;
    *(short8*)(As + i1 * 8) = va1;
    *(short8*)(Bs + i0 * 8) = vb0;
    *(short8*)(Bs + i1 * 8) = vb1;
    __syncthreads();

    short8 af[4], bf[4];
#pragma unroll
    for (int t = 0; t < 4; ++t) {
      af[t] = *(const short8*)(As + (wm + t * 16 + lo) * 32 + quad * 8);
      bf[t] = *(const short8*)(Bs + (wn + t * 16 + lo) * 32 + quad * 8);
    }
#pragma unroll
    for (int mt = 0; mt < 4; ++mt)
#pragma unroll
      for (int nt = 0; nt < 4; ++nt)
        acc[mt][nt] = __builtin_amdgcn_mfma_f32_16x16x32_bf16(af[mt], bf[nt], acc[mt][nt], 0, 0, 0);
  }

#pragma unroll
  for (int mt = 0; mt < 4; ++mt)
#pragma unroll
    for (int nt = 0; nt < 4; ++nt)
#pragma unroll
      for (int r = 0; r < 4; ++r) {
        int row = m0 + wm + mt * 16 + quad * 4 + r;
        int col = n0 + wn + nt * 16 + lo;
        C[(size_t)row * N + col] = f2b(acc[mt][nt][r] + bias[col]);
      }
}

// ---------------------------------------------------------------------------
__global__ void transpose_cast(const float* __restrict__ in, ushort* __restrict__ out,
                               int R, int C)
{
  __shared__ ushort t[64][65];
  const int r0 = blockIdx.y * 64, c0 = blockIdx.x * 64;
  const int tx = threadIdx.x, ty = threadIdx.y;
  for (int i = ty; i < 64; i += 4)
    t[i][tx] = f2b(in[(size_t)(r0 + i) * C + c0 + tx]);
  __syncthreads();
  for (int i = ty; i < 64; i += 4)
    out[(size_t)(c0 + i) * R + r0 + tx] = t[tx][i];
}

__global__ void transpose_bf(const ushort* __restrict__ in, ushort* __restrict__ out,
                             int R, int C, int ldin)
{
  __shared__ ushort t[64][65];
  const int r0 = blockIdx.y * 64, c0 = blockIdx.x * 64;
  const int tx = threadIdx.x, ty = threadIdx.y;
  for (int i = ty; i < 64; i += 4)
    t[i][tx] = in[(size_t)(r0 + i) * ldin + c0 + tx];
  __syncthreads();
  for (int i = ty; i < 64; i += 4)
    out[(size_t)(c0 + i) * R + r0 + tx] = t[tx][i];
}

__global__ void concat_bias(const float* __restrict__ a, const float* __restrict__ b,
                            const float* __restrict__ c, float* __restrict__ o)
{
  const int i = blockIdx.x * 256 + threadIdx.x;
  o[i] = (i < 512) ? a[i] : ((i < 1024) ? b[i - 512] : c[i - 1024]);
}

// ---------------------------------------------------------------------------
// out = LayerNorm(X + Y) * g + b. X fp32/bf16, Y bf16, out fp32/bf16.
// ---------------------------------------------------------------------------
__global__ __launch_bounds__(256) void ln_res(
    const void* __restrict__ Xv, int x_f32, const ushort* __restrict__ Y,
    const float* __restrict__ g, const float* __restrict__ b,
    void* __restrict__ outv, int o_f32)
{
  const int w = threadIdx.x >> 6, lane = threadIdx.x & 63;
  const size_t row = (size_t)blockIdx.x * 4 + w;
  const size_t base = row * 512 + lane * 8;

  float v[8];
  if (x_f32) {
    const float* X = (const float*)Xv + base;
    const float4 x0 = *(const float4*)(X), x1 = *(const float4*)(X + 4);
    v[0] = x0.x; v[1] = x0.y; v[2] = x0.z; v[3] = x0.w;
    v[4] = x1.x; v[5] = x1.y; v[6] = x1.z; v[7] = x1.w;
  } else {
    const short8 xv = *(const short8*)((const ushort*)Xv + base);
#pragma unroll
    for (int j = 0; j < 8; ++j) v[j] = b2f((ushort)xv[j]);
  }
  const short8 yv = *(const short8*)(Y + base);
  float s = 0.f, sq = 0.f;
#pragma unroll
  for (int j = 0; j < 8; ++j) {
    v[j] += b2f((ushort)yv[j]);
    s += v[j]; sq += v[j] * v[j];
  }
  for (int m = 1; m < 64; m <<= 1) {
    s  += __shfl_xor(s,  m, 64);
    sq += __shfl_xor(sq, m, 64);
  }
  const float mean = s * (1.f / 512.f);
  const float var  = sq * (1.f / 512.f) - mean * mean;
  const float rstd = rsqrtf(fmaxf(var, 0.f) + 1e-5f);

  const float4 g0 = *(const float4*)(g + lane * 8);
  const float4 g1 = *(const float4*)(g + lane * 8 + 4);
  const float4 b0 = *(const float4*)(b + lane * 8);
  const float4 b1 = *(const float4*)(b + lane * 8 + 4);
  const float gg[8] = {g0.x, g0.y, g0.z, g0.w, g1.x, g1.y, g1.z, g1.w};
  const float bb[8] = {b0.x, b0.y, b0.z, b0.w, b1.x, b1.y, b1.z, b1.w};

  if (o_f32) {
    float* o = (float*)outv + base;
#pragma unroll
    for (int j = 0; j < 8; ++j) o[j] = (v[j] - mean) * rstd * gg[j] + bb[j];
  } else {
    ushort* o = (ushort*)outv + base;
    short8 ov;
#pragma unroll
    for (int j = 0; j < 8; ++j) ov[j] = (short)f2b((v[j] - mean) * rstd * gg[j] + bb[j]);
    *(short8*)o = ov;
  }
}

// ---------------------------------------------------------------------------
extern "C" void kernel_launch(void* const* d_in, const int* in_sizes, int n_in,
                              void* d_out, int out_size, void* d_ws, size_t ws_size,
                              hipStream_t stream)
{
  const float* x    = (const float*)d_in[0];
  const float* Wq_w = (const float*)d_in[1];
  const float* Wq_b = (const float*)d_in[2];
  const float* Wk_w = (const float*)d_in[3];
  const float* Wk_b = (const float*)d_in[4];
  const float* Wv_w = (const float*)d_in[5];
  const float* Wv_b = (const float*)d_in[6];
  const float* Wu_w = (const float*)d_in[7];
  const float* Wu_b = (const float*)d_in[8];
  const float* g1   = (const float*)d_in[9];
  const float* b1   = (const float*)d_in[10];
  const float* f1w  = (const float*)d_in[11];
  const float* f1b  = (const float*)d_in[12];
  const float* f2w  = (const float*)d_in[13];
  const float* f2bv = (const float*)d_in[14];
  const float* g2   = (const float*)d_in[15];
  const float* b2   = (const float*)d_in[16];

  // Workspace (byte offsets; ws >= 224,401,408 B verified by prior sessions).
  // Attention-phase overlays:
  //   rowsum f32[16384] at 0      (over wqkvt — dead after QKV gemm)
  //   P bf16 [4][4096][4096] at 90,183,680 (over uni..end — all written later)
  char* wsb = (char*)d_ws;
  ushort* wqkvt = (ushort*)(wsb + 0);             // 1536x512   ends   1,572,864
  ushort* wut   = (ushort*)(wsb + 1572864);       //  512x512   ends   2,097,152
  ushort* f1t   = (ushort*)(wsb + 2097152);       // 2048x512   ends   4,194,304
  ushort* f2t   = (ushort*)(wsb + 4194304);       //  512x2048  ends   6,291,456
  float*  bqkv  = (float*) (wsb + 6291456);       // 1536 f32   ends   6,297,600
  ushort* qkv   = (ushort*)(wsb + 6297600);       // 16384x1536 ends  56,629,248
  ushort* vts   = (ushort*)(wsb + 56629248);      // 4x512x4096 ends  73,406,464
  ushort* attn  = (ushort*)(wsb + 73406464);      // 16384x512  ends  90,183,680
  ushort* uni   = (ushort*)(wsb + 90183680);      // 16384x512  ends 106,960,896
  ushort* h     = (ushort*)(wsb + 106960896);     // 16384x512  ends 123,738,112
  ushort* mid   = (ushort*)(wsb + 123738112);     // 16384x2048 ends 190,846,976
  ushort* ffo   = (ushort*)(wsb + 190846976);     // 16384x512  ends 207,624,192
  float*  rowsum = (float*)(wsb + 0);             // 64KB, attention phase only
  ushort* Pbuf   = (ushort*)(wsb + 90183680);     // 134,217,728 B, ends 224,401,408

  const dim3 tb(64, 4);
  transpose_cast<<<dim3(8, 8),  tb, 0, stream>>>(Wq_w, wqkvt,              512, 512);
  transpose_cast<<<dim3(8, 8),  tb, 0, stream>>>(Wk_w, wqkvt + 512 * 512,  512, 512);
  transpose_cast<<<dim3(8, 8),  tb, 0, stream>>>(Wv_w, wqkvt + 1024 * 512, 512, 512);
  transpose_cast<<<dim3(8, 8),  tb, 0, stream>>>(Wu_w, wut, 512, 512);
  transpose_cast<<<dim3(32, 8), tb, 0, stream>>>(f1w, f1t, 512, 2048);
  transpose_cast<<<dim3(8, 32), tb, 0, stream>>>(f2w, f2t, 2048, 512);
  concat_bias<<<6, 256, 0, stream>>>(Wq_b, Wk_b, Wv_b, bqkv);

  // Fused QKV: qkv[16384][1536] = x @ Wqkv^T + b.
  gemm_sync_f32a<<<dim3(12, 128), 256, 0, stream>>>(x, wqkvt, bqkv, qkv, 1536, 512);

  // V^T per batch from strided v (qkv cols 1024..1535).
  for (int b = 0; b < 4; ++b)
    transpose_bf<<<dim3(8, 64), tb, 0, stream>>>(
        qkv + (size_t)b * 4096 * 1536 + 1024, vts + (size_t)b * 512 * 4096,
        4096, 512, 1536);

  // Attention: P = exp(QK^T/8) -> rowsums -> attn = P@V / rowsum.
  gemm_qk_exp<<<4096, 256, 0, stream>>>(qkv, Pbuf);
  row_sums<<<4096, 256, 0, stream>>>(Pbuf, rowsum);
  gemm_pv_norm<<<512, 256, 0, stream>>>(Pbuf, vts, rowsum, attn);

  // Output projection + residual LN1.
  gemm_async<<<512, 256, 0, stream>>>(attn, wut, Wu_b, uni,
      512, 512, 512, 512, 2, 7, 1.f, 0);
  ln_res<<<4096, 256, 0, stream>>>(x, 1, uni, g1, b1, h, 0);

  // FFN + residual LN2 -> d_out (fp32).
  gemm_async<<<2048, 256, 0, stream>>>(h, f1t, f1b, mid,
      2048, 512, 512, 512, 4, 7, 1.f, GF_RELU);
  gemm_async<<<512, 256, 0, stream>>>(mid, f2t, f2bv, ffo,
      512, 2048, 2048, 2048, 2, 7, 1.f, 0);
  ln_res<<<4096, 256, 0, stream>>>(h, 0, ffo, g2, b2, d_out, 1);
}

// Round 6
// 564.161 us; speedup vs baseline: 2.6988x; 1.1313x over previous
//
#include <hip/hip_runtime.h>

#define AS1 __attribute__((address_space(1)))
#define AS3 __attribute__((address_space(3)))

typedef __attribute__((ext_vector_type(8))) short short8;
typedef __attribute__((ext_vector_type(4))) float floatx4;

__device__ __forceinline__ float b2f(ushort u) {
  union { unsigned int i; float f; } x; x.i = ((unsigned int)u) << 16; return x.f;
}
__device__ __forceinline__ ushort f2b(float f) {
  union { float f; unsigned int i; } x; x.f = f;
  unsigned int r = (x.i + 0x7fffu + ((x.i >> 16) & 1u)) >> 16;
  return (ushort)r;
}

#define GF_RELU 1

// ---------------------------------------------------------------------------
// v7: attention as GEMM passes with algebraic Wu-fusion.
//   (P@V)/rs @ Wu + b  ==  (P @ (V@Wu))/rs + b      (rs is per-row scalar)
//   A: VWt = wut . V^T          (tiny GEMM from qkv; replaces transpose_bf)
//   B: P = exp(QK^T/8), rowsum partials atomicAdd'd in epilogue (no 2nd read)
//   C: uni = (P @ VWt)/rs + Wu_b  directly (Wu GEMM + attn buffer deleted)
// v6 post-mortem: gemm_pv_norm FETCH=330MB = 2.4x P; the 4 col-tiles of each
// P row-panel landed on 4 different XCDs (consecutive ids round-robin) ->
// per-XCD L2 re-fetch. v7 pv swizzle: each XCD owns whole row-panels (all 4
// col-tiles share its L2; 64 blocks/XCD all co-resident). pv also moves to
// BK=64 (64 barrier drains instead of 128) with the flash-proven 16B-chunk
// XOR swizzle (source-side + read-side) to keep LDS reads ~2-way.
// ---------------------------------------------------------------------------

__global__ void zero_f32(float* __restrict__ p)
{
  p[blockIdx.x * 256 + threadIdx.x] = 0.f;
}

// Pass A: VWt[b][c][j] = sum_d Wu[d][c] * V[b][j][d].
// NT GEMM: A = wut (M=512, lda=512), Bt = qkv v-cols (N=4096, ldb=1536), K=512.
// Grid 512 = 4 batches x (32 j-tiles x 4 c-tiles).
__global__ __launch_bounds__(256) void gemm_vw(
    const ushort* __restrict__ qkv, const ushort* __restrict__ wut,
    ushort* __restrict__ vwt)
{
  __shared__ __align__(16) ushort As[128 * 32];
  __shared__ __align__(16) ushort Bs[128 * 32];

  const int id = blockIdx.x;
  const int b  = id >> 7;
  const int t  = id & 127;
  const int bx = t & 31;              // j tile
  const int by = t >> 5;              // c tile

  const ushort* A  = wut;
  const ushort* Bt = qkv + (size_t)b * 4096 * 1536 + 1024;
  ushort* C = vwt + (size_t)b * 512 * 4096;

  const int tid  = threadIdx.x;
  const int w    = tid >> 6;
  const int lane = tid & 63;
  const int lo   = lane & 15;
  const int quad = lane >> 4;
  const int m0   = by * 128;
  const int n0   = bx * 128;
  const int wm   = (w & 1) * 64;
  const int wn   = (w >> 1) * 64;

  const int i0 = tid, i1 = tid + 256;
  const ushort* ga0 = A  + (size_t)(m0 + (i0 >> 2)) * 512 + ((i0 & 3) << 3);
  const ushort* ga1 = A  + (size_t)(m0 + (i1 >> 2)) * 512 + ((i1 & 3) << 3);
  const ushort* gb0 = Bt + (size_t)(n0 + (i0 >> 2)) * 1536 + ((i0 & 3) << 3);
  const ushort* gb1 = Bt + (size_t)(n0 + (i1 >> 2)) * 1536 + ((i1 & 3) << 3);

  floatx4 acc[4][4] = {};

  for (int k0 = 0; k0 < 512; k0 += 32) {
    __syncthreads();
    __builtin_amdgcn_global_load_lds((const AS1 void*)(ga0 + k0), (AS3 void*)(As + i0 * 8), 16, 0, 0);
    __builtin_amdgcn_global_load_lds((const AS1 void*)(ga1 + k0), (AS3 void*)(As + i1 * 8), 16, 0, 0);
    __builtin_amdgcn_global_load_lds((const AS1 void*)(gb0 + k0), (AS3 void*)(Bs + i0 * 8), 16, 0, 0);
    __builtin_amdgcn_global_load_lds((const AS1 void*)(gb1 + k0), (AS3 void*)(Bs + i1 * 8), 16, 0, 0);
    __syncthreads();

    short8 af[4], bf[4];
#pragma unroll
    for (int tt = 0; tt < 4; ++tt) {
      af[tt] = *(const short8*)(As + (wm + tt * 16 + lo) * 32 + quad * 8);
      bf[tt] = *(const short8*)(Bs + (wn + tt * 16 + lo) * 32 + quad * 8);
    }
#pragma unroll
    for (int mt = 0; mt < 4; ++mt)
#pragma unroll
      for (int nt = 0; nt < 4; ++nt)
        acc[mt][nt] = __builtin_amdgcn_mfma_f32_16x16x32_bf16(af[mt], bf[nt], acc[mt][nt], 0, 0, 0);
  }

#pragma unroll
  for (int mt = 0; mt < 4; ++mt)
#pragma unroll
    for (int nt = 0; nt < 4; ++nt)
#pragma unroll
      for (int r = 0; r < 4; ++r) {
        const int row = m0 + wm + mt * 16 + quad * 4 + r;
        const int col = n0 + wn + nt * 16 + lo;
        C[(size_t)row * 4096 + col] = f2b(acc[mt][nt][r]);
      }
}

// Pass B: P = exp((Q.K^T)/8); per-row partial sums atomicAdd'd to rs.
// A=Q (qkv cols 0..511), Bt=K (qkv cols 512..1023), lda=ldb=1536.
// Per batch M=N=4096, K=512. Grid 4096 = 4 batches x 32x32 (XCD swizzle).
__global__ __launch_bounds__(256) void gemm_qk_exp(
    const ushort* __restrict__ qkv, ushort* __restrict__ P,
    float* __restrict__ rs)
{
  __shared__ __align__(16) ushort As[128 * 32];
  __shared__ __align__(16) ushort Bs[128 * 32];

  const int id = blockIdx.x;
  const int b  = id >> 10;            // batch
  const int t  = id & 1023;
  const int r8 = t & 7;               // XCD swizzle
  const int s2 = t >> 3;
  const int bx = s2 & 31;
  const int by = r8 + ((s2 >> 5) << 3);

  const ushort* A  = qkv + (size_t)b * 4096 * 1536;        // Q rows
  const ushort* Bt = qkv + (size_t)b * 4096 * 1536 + 512;  // K rows
  ushort* C = P + (size_t)b * 4096 * 4096;

  const int tid  = threadIdx.x;
  const int w    = tid >> 6;
  const int lane = tid & 63;
  const int lo   = lane & 15;
  const int quad = lane >> 4;
  const int m0   = by * 128;
  const int n0   = bx * 128;
  const int wm   = (w & 1) * 64;
  const int wn   = (w >> 1) * 64;

  const int i0 = tid, i1 = tid + 256;
  const ushort* ga0 = A  + (size_t)(m0 + (i0 >> 2)) * 1536 + ((i0 & 3) << 3);
  const ushort* ga1 = A  + (size_t)(m0 + (i1 >> 2)) * 1536 + ((i1 & 3) << 3);
  const ushort* gb0 = Bt + (size_t)(n0 + (i0 >> 2)) * 1536 + ((i0 & 3) << 3);
  const ushort* gb1 = Bt + (size_t)(n0 + (i1 >> 2)) * 1536 + ((i1 & 3) << 3);

  floatx4 acc[4][4] = {};

  for (int k0 = 0; k0 < 512; k0 += 32) {
    __syncthreads();
    __builtin_amdgcn_global_load_lds((const AS1 void*)(ga0 + k0), (AS3 void*)(As + i0 * 8), 16, 0, 0);
    __builtin_amdgcn_global_load_lds((const AS1 void*)(ga1 + k0), (AS3 void*)(As + i1 * 8), 16, 0, 0);
    __builtin_amdgcn_global_load_lds((const AS1 void*)(gb0 + k0), (AS3 void*)(Bs + i0 * 8), 16, 0, 0);
    __builtin_amdgcn_global_load_lds((const AS1 void*)(gb1 + k0), (AS3 void*)(Bs + i1 * 8), 16, 0, 0);
    __syncthreads();

    short8 af[4], bf[4];
#pragma unroll
    for (int tt = 0; tt < 4; ++tt) {
      af[tt] = *(const short8*)(As + (wm + tt * 16 + lo) * 32 + quad * 8);
      bf[tt] = *(const short8*)(Bs + (wn + tt * 16 + lo) * 32 + quad * 8);
    }
#pragma unroll
    for (int mt = 0; mt < 4; ++mt)
#pragma unroll
      for (int nt = 0; nt < 4; ++nt)
        acc[mt][nt] = __builtin_amdgcn_mfma_f32_16x16x32_bf16(af[mt], bf[nt], acc[mt][nt], 0, 0, 0);
  }

#pragma unroll
  for (int mt = 0; mt < 4; ++mt)
#pragma unroll
    for (int r = 0; r < 4; ++r) {
      const int row = m0 + wm + mt * 16 + quad * 4 + r;
      float esum = 0.f;
#pragma unroll
      for (int nt = 0; nt < 4; ++nt) {
        const int col = n0 + wn + nt * 16 + lo;
        const float e = __expf(acc[mt][nt][r] * 0.125f);
        esum += e;
        C[(size_t)row * 4096 + col] = f2b(e);
      }
      esum += __shfl_xor(esum, 1, 64);
      esum += __shfl_xor(esum, 2, 64);
      esum += __shfl_xor(esum, 4, 64);
      esum += __shfl_xor(esum, 8, 64);
      if (lo == 0) atomicAdd(&rs[(size_t)b * 4096 + row], esum);
    }
}

// Pass C: uni = (P @ VWt)/rs + Wu_b. A=P (lda 4096), Bt=vwt (ldb 4096),
// per batch M=4096, N=512, K=4096, BK=64 with 16B-chunk XOR swizzle.
// XCD-panel swizzle: xcd=id&7 owns 16 whole row-panels (all 4 col-tiles on
// the same L2; 64 blocks/XCD all co-resident at 2 blk/CU x 32 CU).
__global__ __launch_bounds__(256) void gemm_pv_wu(
    const ushort* __restrict__ P, const ushort* __restrict__ vwt,
    const float* __restrict__ rs, const float* __restrict__ bias,
    ushort* __restrict__ uni)
{
  __shared__ __align__(16) ushort As[128 * 64];
  __shared__ __align__(16) ushort Bs[128 * 64];

  const int id  = blockIdx.x;         // 0..511
  const int xcd = id & 7;
  const int s   = id >> 3;            // 0..63
  const int bx  = s & 3;              // col tile
  const int panel = xcd * 16 + (s >> 2);  // 0..127
  const int b  = panel >> 5;
  const int by = panel & 31;

  const ushort* A  = P   + (size_t)b * 4096 * 4096;
  const ushort* Bt = vwt + (size_t)b * 512 * 4096;

  const int tid  = threadIdx.x;
  const int w    = tid >> 6;
  const int lane = tid & 63;
  const int lo   = lane & 15;
  const int quad = lane >> 4;
  const int m0   = by * 128;
  const int n0   = bx * 128;
  const int wm   = (w & 1) * 64;
  const int wn   = (w >> 1) * 64;

  // Staging geometry: 1024 16B-chunks per tile; chunk s_ -> row=s_>>3, sl=s_&7;
  // source chunk = sl ^ (row&7) (inverse swizzle), LDS stays linear.
  const ushort* gaP[4]; const ushort* gbP[4];
#pragma unroll
  for (int k = 0; k < 4; ++k) {
    const int s_ = tid + k * 256;
    const int row = s_ >> 3, sl = s_ & 7;
    gaP[k] = A  + (size_t)(m0 + row) * 4096 + ((sl ^ (row & 7)) << 3);
    gbP[k] = Bt + (size_t)(n0 + row) * 4096 + ((sl ^ (row & 7)) << 3);
  }

  floatx4 acc[4][4] = {};

  for (int k0 = 0; k0 < 4096; k0 += 64) {
    __syncthreads();
#pragma unroll
    for (int k = 0; k < 4; ++k) {
      const int s_ = tid + k * 256;
      __builtin_amdgcn_global_load_lds((const AS1 void*)(gaP[k] + k0), (AS3 void*)(As + s_ * 8), 16, 0, 0);
      __builtin_amdgcn_global_load_lds((const AS1 void*)(gbP[k] + k0), (AS3 void*)(Bs + s_ * 8), 16, 0, 0);
    }
    __syncthreads();

#pragma unroll
    for (int kk = 0; kk < 2; ++kk) {
      short8 af[4], bf[4];
#pragma unroll
      for (int tt = 0; tt < 4; ++tt) {
        const int ra = wm + tt * 16 + lo;
        const int rb = wn + tt * 16 + lo;
        af[tt] = *(const short8*)(As + (size_t)ra * 64 + (((kk * 4 + quad) ^ (ra & 7)) << 3));
        bf[tt] = *(const short8*)(Bs + (size_t)rb * 64 + (((kk * 4 + quad) ^ (rb & 7)) << 3));
      }
#pragma unroll
      for (int mt = 0; mt < 4; ++mt)
#pragma unroll
        for (int nt = 0; nt < 4; ++nt)
          acc[mt][nt] = __builtin_amdgcn_mfma_f32_16x16x32_bf16(af[mt], bf[nt], acc[mt][nt], 0, 0, 0);
    }
  }

#pragma unroll
  for (int mt = 0; mt < 4; ++mt)
#pragma unroll
    for (int r = 0; r < 4; ++r) {
      const int row = m0 + wm + mt * 16 + quad * 4 + r;
      const size_t grow = (size_t)b * 4096 + row;
      const float inv = 1.f / rs[grow];
#pragma unroll
      for (int nt = 0; nt < 4; ++nt) {
        const int col = n0 + wn + nt * 16 + lo;
        uni[grow * 512 + col] = f2b(acc[mt][nt][r] * inv + bias[col]);
      }
    }
}

// ---------------------------------------------------------------------------
// Async NT GEMM, flat grid with XCD swizzle (FF1 / FF2).
// ---------------------------------------------------------------------------
__global__ __launch_bounds__(256) void gemm_async(
    const ushort* __restrict__ A, const ushort* __restrict__ Bt,
    const float* __restrict__ bias, ushort* __restrict__ C,
    int N, int K, int lda, int ldb,
    int lg_gx, int lg_gy, float scale, int flags)
{
  __shared__ __align__(16) ushort As[128 * 32];
  __shared__ __align__(16) ushort Bs[128 * 32];

  const int id = blockIdx.x;
  const int r8 = id & 7;
  const int s  = id >> 3;
  const int bx = s & ((1 << lg_gx) - 1);
  const int j  = r8 + ((s >> lg_gx) << 3);
  const int by = j & ((1 << lg_gy) - 1);

  const int tid  = threadIdx.x;
  const int w    = tid >> 6;
  const int lane = tid & 63;
  const int lo   = lane & 15;
  const int quad = lane >> 4;
  const int m0   = by * 128;
  const int n0   = bx * 128;
  const int wm   = (w & 1) * 64;
  const int wn   = (w >> 1) * 64;

  const int i0 = tid, i1 = tid + 256;
  const ushort* ga0 = A  + (size_t)(m0 + (i0 >> 2)) * lda + ((i0 & 3) << 3);
  const ushort* ga1 = A  + (size_t)(m0 + (i1 >> 2)) * lda + ((i1 & 3) << 3);
  const ushort* gb0 = Bt + (size_t)(n0 + (i0 >> 2)) * ldb + ((i0 & 3) << 3);
  const ushort* gb1 = Bt + (size_t)(n0 + (i1 >> 2)) * ldb + ((i1 & 3) << 3);

  floatx4 acc[4][4] = {};

  for (int k0 = 0; k0 < K; k0 += 32) {
    __syncthreads();
    __builtin_amdgcn_global_load_lds((const AS1 void*)(ga0 + k0), (AS3 void*)(As + i0 * 8), 16, 0, 0);
    __builtin_amdgcn_global_load_lds((const AS1 void*)(ga1 + k0), (AS3 void*)(As + i1 * 8), 16, 0, 0);
    __builtin_amdgcn_global_load_lds((const AS1 void*)(gb0 + k0), (AS3 void*)(Bs + i0 * 8), 16, 0, 0);
    __builtin_amdgcn_global_load_lds((const AS1 void*)(gb1 + k0), (AS3 void*)(Bs + i1 * 8), 16, 0, 0);
    __syncthreads();

    short8 af[4], bf[4];
#pragma unroll
    for (int t = 0; t < 4; ++t) {
      af[t] = *(const short8*)(As + (wm + t * 16 + lo) * 32 + quad * 8);
      bf[t] = *(const short8*)(Bs + (wn + t * 16 + lo) * 32 + quad * 8);
    }
#pragma unroll
    for (int mt = 0; mt < 4; ++mt)
#pragma unroll
      for (int nt = 0; nt < 4; ++nt)
        acc[mt][nt] = __builtin_amdgcn_mfma_f32_16x16x32_bf16(af[mt], bf[nt], acc[mt][nt], 0, 0, 0);
  }

#pragma unroll
  for (int mt = 0; mt < 4; ++mt)
#pragma unroll
    for (int nt = 0; nt < 4; ++nt)
#pragma unroll
      for (int r = 0; r < 4; ++r) {
        int row = m0 + wm + mt * 16 + quad * 4 + r;
        int col = n0 + wn + nt * 16 + lo;
        float v = acc[mt][nt][r] * scale;
        if (bias) v += bias[col];
        if (flags & GF_RELU) v = fmaxf(v, 0.f);
        C[(size_t)row * N + col] = f2b(v);
      }
}

// ---------------------------------------------------------------------------
// Sync NT GEMM with fp32 A (cast in staging) — fused QKV projection.
// ---------------------------------------------------------------------------
__global__ __launch_bounds__(256) void gemm_sync_f32a(
    const float* __restrict__ Af, const ushort* __restrict__ Bt,
    const float* __restrict__ bias, ushort* __restrict__ C,
    int N, int K)
{
  __shared__ __align__(16) ushort As[128 * 32];
  __shared__ __align__(16) ushort Bs[128 * 32];

  const int tid  = threadIdx.x;
  const int w    = tid >> 6;
  const int lane = tid & 63;
  const int lo   = lane & 15;
  const int quad = lane >> 4;
  const int m0   = blockIdx.y * 128;
  const int n0   = blockIdx.x * 128;
  const int wm   = (w & 1) * 64;
  const int wn   = (w >> 1) * 64;

  const int i0 = tid, i1 = tid + 256;
  const size_t aoff0 = (size_t)(m0 + (i0 >> 2)) * K + ((i0 & 3) << 3);
  const size_t aoff1 = (size_t)(m0 + (i1 >> 2)) * K + ((i1 & 3) << 3);
  const size_t boff0 = (size_t)(n0 + (i0 >> 2)) * K + ((i0 & 3) << 3);
  const size_t boff1 = (size_t)(n0 + (i1 >> 2)) * K + ((i1 & 3) << 3);

  floatx4 acc[4][4] = {};

  for (int k0 = 0; k0 < K; k0 += 32) {
    short8 va0, va1;
    const float4 a00 = *(const float4*)(Af + aoff0 + k0);
    const float4 a01 = *(const float4*)(Af + aoff0 + k0 + 4);
    const float4 a10 = *(const float4*)(Af + aoff1 + k0);
    const float4 a11 = *(const float4*)(Af + aoff1 + k0 + 4);
    va0[0] = (short)f2b(a00.x); va0[1] = (short)f2b(a00.y);
    va0[2] = (short)f2b(a00.z); va0[3] = (short)f2b(a00.w);
    va0[4] = (short)f2b(a01.x); va0[5] = (short)f2b(a01.y);
    va0[6] = (short)f2b(a01.z); va0[7] = (short)f2b(a01.w);
    va1[0] = (short)f2b(a10.x); va1[1] = (short)f2b(a10.y);
    va1[2] = (short)f2b(a10.z); va1[3] = (short)f2b(a10.w);
    va1[4] = (short)f2b(a11.x); va1[5] = (short)f2b(a11.y);
    va1[6] = (short)f2b(a11.z); va1[7] = (short)f2b(a11.w);
    const short8 vb0 = *(const short8*)(Bt + boff0 + k0);
    const short8 vb1 = *(const short8*)(Bt + boff1 + k0);
    __syncthreads();
    *(short8*)(As + i0 * 8) = va0;
    *(short8*)(As + i1 * 8) = va1;
    *(short8*)(Bs + i0 * 8) = vb0;
    *(short8*)(Bs + i1 * 8) = vb1;
    __syncthreads();

    short8 af[4], bf[4];
#pragma unroll
    for (int t = 0; t < 4; ++t) {
      af[t] = *(const short8*)(As + (wm + t * 16 + lo) * 32 + quad * 8);
      bf[t] = *(const short8*)(Bs + (wn + t * 16 + lo) * 32 + quad * 8);
    }
#pragma unroll
    for (int mt = 0; mt < 4; ++mt)
#pragma unroll
      for (int nt = 0; nt < 4; ++nt)
        acc[mt][nt] = __builtin_amdgcn_mfma_f32_16x16x32_bf16(af[mt], bf[nt], acc[mt][nt], 0, 0, 0);
  }

#pragma unroll
  for (int mt = 0; mt < 4; ++mt)
#pragma unroll
    for (int nt = 0; nt < 4; ++nt)
#pragma unroll
      for (int r = 0; r < 4; ++r) {
        int row = m0 + wm + mt * 16 + quad * 4 + r;
        int col = n0 + wn + nt * 16 + lo;
        C[(size_t)row * N + col] = f2b(acc[mt][nt][r] + bias[col]);
      }
}

// ---------------------------------------------------------------------------
__global__ void transpose_cast(const float* __restrict__ in, ushort* __restrict__ out,
                               int R, int C)
{
  __shared__ ushort t[64][65];
  const int r0 = blockIdx.y * 64, c0 = blockIdx.x * 64;
  const int tx = threadIdx.x, ty = threadIdx.y;
  for (int i = ty; i < 64; i += 4)
    t[i][tx] = f2b(in[(size_t)(r0 + i) * C + c0 + tx]);
  __syncthreads();
  for (int i = ty; i < 64; i += 4)
    out[(size_t)(c0 + i) * R + r0 + tx] = t[tx][i];
}

__global__ void concat_bias(const float* __restrict__ a, const float* __restrict__ b,
                            const float* __restrict__ c, float* __restrict__ o)
{
  const int i = blockIdx.x * 256 + threadIdx.x;
  o[i] = (i < 512) ? a[i] : ((i < 1024) ? b[i - 512] : c[i - 1024]);
}

// ---------------------------------------------------------------------------
// out = LayerNorm(X + Y) * g + b. X fp32/bf16, Y bf16, out fp32/bf16.
// ---------------------------------------------------------------------------
__global__ __launch_bounds__(256) void ln_res(
    const void* __restrict__ Xv, int x_f32, const ushort* __restrict__ Y,
    const float* __restrict__ g, const float* __restrict__ b,
    void* __restrict__ outv, int o_f32)
{
  const int w = threadIdx.x >> 6, lane = threadIdx.x & 63;
  const size_t row = (size_t)blockIdx.x * 4 + w;
  const size_t base = row * 512 + lane * 8;

  float v[8];
  if (x_f32) {
    const float* X = (const float*)Xv + base;
    const float4 x0 = *(const float4*)(X), x1 = *(const float4*)(X + 4);
    v[0] = x0.x; v[1] = x0.y; v[2] = x0.z; v[3] = x0.w;
    v[4] = x1.x; v[5] = x1.y; v[6] = x1.z; v[7] = x1.w;
  } else {
    const short8 xv = *(const short8*)((const ushort*)Xv + base);
#pragma unroll
    for (int j = 0; j < 8; ++j) v[j] = b2f((ushort)xv[j]);
  }
  const short8 yv = *(const short8*)(Y + base);
  float s = 0.f, sq = 0.f;
#pragma unroll
  for (int j = 0; j < 8; ++j) {
    v[j] += b2f((ushort)yv[j]);
    s += v[j]; sq += v[j] * v[j];
  }
  for (int m = 1; m < 64; m <<= 1) {
    s  += __shfl_xor(s,  m, 64);
    sq += __shfl_xor(sq, m, 64);
  }
  const float mean = s * (1.f / 512.f);
  const float var  = sq * (1.f / 512.f) - mean * mean;
  const float rstd = rsqrtf(fmaxf(var, 0.f) + 1e-5f);

  const float4 g0 = *(const float4*)(g + lane * 8);
  const float4 g1 = *(const float4*)(g + lane * 8 + 4);
  const float4 b0 = *(const float4*)(b + lane * 8);
  const float4 b1 = *(const float4*)(b + lane * 8 + 4);
  const float gg[8] = {g0.x, g0.y, g0.z, g0.w, g1.x, g1.y, g1.z, g1.w};
  const float bb[8] = {b0.x, b0.y, b0.z, b0.w, b1.x, b1.y, b1.z, b1.w};

  if (o_f32) {
    float* o = (float*)outv + base;
#pragma unroll
    for (int j = 0; j < 8; ++j) o[j] = (v[j] - mean) * rstd * gg[j] + bb[j];
  } else {
    ushort* o = (ushort*)outv + base;
    short8 ov;
#pragma unroll
    for (int j = 0; j < 8; ++j) ov[j] = (short)f2b((v[j] - mean) * rstd * gg[j] + bb[j]);
    *(short8*)o = ov;
  }
}

// ---------------------------------------------------------------------------
extern "C" void kernel_launch(void* const* d_in, const int* in_sizes, int n_in,
                              void* d_out, int out_size, void* d_ws, size_t ws_size,
                              hipStream_t stream)
{
  const float* x    = (const float*)d_in[0];
  const float* Wq_w = (const float*)d_in[1];
  const float* Wq_b = (const float*)d_in[2];
  const float* Wk_w = (const float*)d_in[3];
  const float* Wk_b = (const float*)d_in[4];
  const float* Wv_w = (const float*)d_in[5];
  const float* Wv_b = (const float*)d_in[6];
  const float* Wu_w = (const float*)d_in[7];
  const float* Wu_b = (const float*)d_in[8];
  const float* g1   = (const float*)d_in[9];
  const float* b1   = (const float*)d_in[10];
  const float* f1w  = (const float*)d_in[11];
  const float* f1b  = (const float*)d_in[12];
  const float* f2w  = (const float*)d_in[13];
  const float* f2bv = (const float*)d_in[14];
  const float* g2   = (const float*)d_in[15];
  const float* b2   = (const float*)d_in[16];

  // Workspace (byte offsets; ws >= 224,401,408 B verified).
  // Attention-phase overlays:
  //   rowsum f32[16384] at 0 (over wqkvt — dead after QKV gemm)
  //   Pbuf bf16 4x4096x4096 at 90,183,680..224,401,408 (h/mid/ffo written after)
  //   uni moved to the old attn slot (73,406,464) so pv can write while P lives
  char* wsb = (char*)d_ws;
  ushort* wqkvt = (ushort*)(wsb + 0);             // 1536x512   ends   1,572,864
  ushort* wut   = (ushort*)(wsb + 1572864);       //  512x512   ends   2,097,152
  ushort* f1t   = (ushort*)(wsb + 2097152);       // 2048x512   ends   4,194,304
  ushort* f2t   = (ushort*)(wsb + 4194304);       //  512x2048  ends   6,291,456
  float*  bqkv  = (float*) (wsb + 6291456);       // 1536 f32   ends   6,297,600
  ushort* qkv   = (ushort*)(wsb + 6297600);       // 16384x1536 ends  56,629,248
  ushort* vwt   = (ushort*)(wsb + 56629248);      // 4x512x4096 ends  73,406,464
  ushort* uni   = (ushort*)(wsb + 73406464);      // 16384x512  ends  90,183,680
  ushort* h     = (ushort*)(wsb + 106960896);     // 16384x512  ends 123,738,112
  ushort* mid   = (ushort*)(wsb + 123738112);     // 16384x2048 ends 190,846,976
  ushort* ffo   = (ushort*)(wsb + 190846976);     // 16384x512  ends 207,624,192
  float*  rowsum = (float*)(wsb + 0);             // 64KB, attention phase only
  ushort* Pbuf   = (ushort*)(wsb + 90183680);     // 134,217,728 B, ends 224,401,408

  const dim3 tb(64, 4);
  transpose_cast<<<dim3(8, 8),  tb, 0, stream>>>(Wq_w, wqkvt,              512, 512);
  transpose_cast<<<dim3(8, 8),  tb, 0, stream>>>(Wk_w, wqkvt + 512 * 512,  512, 512);
  transpose_cast<<<dim3(8, 8),  tb, 0, stream>>>(Wv_w, wqkvt + 1024 * 512, 512, 512);
  transpose_cast<<<dim3(8, 8),  tb, 0, stream>>>(Wu_w, wut, 512, 512);
  transpose_cast<<<dim3(32, 8), tb, 0, stream>>>(f1w, f1t, 512, 2048);
  transpose_cast<<<dim3(8, 32), tb, 0, stream>>>(f2w, f2t, 2048, 512);
  concat_bias<<<6, 256, 0, stream>>>(Wq_b, Wk_b, Wv_b, bqkv);

  // Fused QKV: qkv[16384][1536] = x @ Wqkv^T + b.
  gemm_sync_f32a<<<dim3(12, 128), 256, 0, stream>>>(x, wqkvt, bqkv, qkv, 1536, 512);

  // Attention with fused Wu: VWt -> P(+rowsum) -> uni = (P@VWt)/rs + Wu_b.
  zero_f32<<<64, 256, 0, stream>>>(rowsum);
  gemm_vw<<<512, 256, 0, stream>>>(qkv, wut, vwt);
  gemm_qk_exp<<<4096, 256, 0, stream>>>(qkv, Pbuf, rowsum);
  gemm_pv_wu<<<512, 256, 0, stream>>>(Pbuf, vwt, rowsum, Wu_b, uni);

  // Residual LN1.
  ln_res<<<4096, 256, 0, stream>>>(x, 1, uni, g1, b1, h, 0);

  // FFN + residual LN2 -> d_out (fp32).
  gemm_async<<<2048, 256, 0, stream>>>(h, f1t, f1b, mid,
      2048, 512, 512, 512, 4, 7, 1.f, GF_RELU);
  gemm_async<<<512, 256, 0, stream>>>(mid, f2t, f2bv, ffo,
      512, 2048, 2048, 2048, 2, 7, 1.f, 0);
  ln_res<<<4096, 256, 0, stream>>>(h, 0, ffo, g2, b2, d_out, 1);
}

// Round 8
// 512.057 us; speedup vs baseline: 2.9734x; 1.1018x over previous
//
#include <hip/hip_runtime.h>

#define AS1 __attribute__((address_space(1)))
#define AS3 __attribute__((address_space(3)))

typedef __attribute__((ext_vector_type(8))) short short8;
typedef __attribute__((ext_vector_type(4))) float floatx4;

__device__ __forceinline__ float b2f(ushort u) {
  union { unsigned int i; float f; } x; x.i = ((unsigned int)u) << 16; return x.f;
}
__device__ __forceinline__ ushort f2b(float f) {
  union { float f; unsigned int i; } x; x.f = f;
  unsigned int r = (x.i + 0x7fffu + ((x.i >> 16) & 1u)) >> 16;
  return (ushort)r;
}

#define GF_RELU 1

// ---------------------------------------------------------------------------
// v8 (resubmit; r7 bench was an infra failure, "container failed twice"):
// all heavy GEMMs on the BK=64 XOR-swizzle staging structure (proven in
// v7's gemm_pv_wu); rowsum moved INTO pv via MFMA-with-ones.
//   qk_exp:  P = exp(QK^T/8) only (epilogue shuffles/atomics deleted)
//   pv_wu:   rs[row] = P-row . ones computed by 8 extra MFMA/iter (idle pipe),
//            block-local rsm[128] in LDS -> uni = (P@VWt)/rs + Wu_b
//   FF1/FF2: gemm_async64 (BK=64, halved barrier drains)
// v7 counters: qk 143us MfmaUtil 19.7 VALU 21 (BK=32 + epilogue reduction);
// pv out of top-5 (panel swizzle + BK=64 worked).
// ---------------------------------------------------------------------------

// Pass A: VWt[b][c][j] = sum_d Wu[d][c] * V[b][j][d].  (tiny; BK=32 skeleton)
__global__ __launch_bounds__(256) void gemm_vw(
    const ushort* __restrict__ qkv, const ushort* __restrict__ wut,
    ushort* __restrict__ vwt)
{
  __shared__ __align__(16) ushort As[128 * 32];
  __shared__ __align__(16) ushort Bs[128 * 32];

  const int id = blockIdx.x;
  const int b  = id >> 7;
  const int t  = id & 127;
  const int bx = t & 31;              // j tile
  const int by = t >> 5;              // c tile

  const ushort* A  = wut;
  const ushort* Bt = qkv + (size_t)b * 4096 * 1536 + 1024;
  ushort* C = vwt + (size_t)b * 512 * 4096;

  const int tid  = threadIdx.x;
  const int w    = tid >> 6;
  const int lane = tid & 63;
  const int lo   = lane & 15;
  const int quad = lane >> 4;
  const int m0   = by * 128;
  const int n0   = bx * 128;
  const int wm   = (w & 1) * 64;
  const int wn   = (w >> 1) * 64;

  const int i0 = tid, i1 = tid + 256;
  const ushort* ga0 = A  + (size_t)(m0 + (i0 >> 2)) * 512 + ((i0 & 3) << 3);
  const ushort* ga1 = A  + (size_t)(m0 + (i1 >> 2)) * 512 + ((i1 & 3) << 3);
  const ushort* gb0 = Bt + (size_t)(n0 + (i0 >> 2)) * 1536 + ((i0 & 3) << 3);
  const ushort* gb1 = Bt + (size_t)(n0 + (i1 >> 2)) * 1536 + ((i1 & 3) << 3);

  floatx4 acc[4][4] = {};

  for (int k0 = 0; k0 < 512; k0 += 32) {
    __syncthreads();
    __builtin_amdgcn_global_load_lds((const AS1 void*)(ga0 + k0), (AS3 void*)(As + i0 * 8), 16, 0, 0);
    __builtin_amdgcn_global_load_lds((const AS1 void*)(ga1 + k0), (AS3 void*)(As + i1 * 8), 16, 0, 0);
    __builtin_amdgcn_global_load_lds((const AS1 void*)(gb0 + k0), (AS3 void*)(Bs + i0 * 8), 16, 0, 0);
    __builtin_amdgcn_global_load_lds((const AS1 void*)(gb1 + k0), (AS3 void*)(Bs + i1 * 8), 16, 0, 0);
    __syncthreads();

    short8 af[4], bf[4];
#pragma unroll
    for (int tt = 0; tt < 4; ++tt) {
      af[tt] = *(const short8*)(As + (wm + tt * 16 + lo) * 32 + quad * 8);
      bf[tt] = *(const short8*)(Bs + (wn + tt * 16 + lo) * 32 + quad * 8);
    }
#pragma unroll
    for (int mt = 0; mt < 4; ++mt)
#pragma unroll
      for (int nt = 0; nt < 4; ++nt)
        acc[mt][nt] = __builtin_amdgcn_mfma_f32_16x16x32_bf16(af[mt], bf[nt], acc[mt][nt], 0, 0, 0);
  }

#pragma unroll
  for (int mt = 0; mt < 4; ++mt)
#pragma unroll
    for (int nt = 0; nt < 4; ++nt)
#pragma unroll
      for (int r = 0; r < 4; ++r) {
        const int row = m0 + wm + mt * 16 + quad * 4 + r;
        const int col = n0 + wn + nt * 16 + lo;
        C[(size_t)row * 4096 + col] = f2b(acc[mt][nt][r]);
      }
}

// Pass B: P = exp((Q.K^T)/8). BK=64 XOR-swizzle staging; pure exp+store
// epilogue (rowsum moved to pv pass). Grid 4096 = 4 batches x 32x32 (XCD swz).
__global__ __launch_bounds__(256) void gemm_qk_exp(
    const ushort* __restrict__ qkv, ushort* __restrict__ P)
{
  __shared__ __align__(16) ushort As[128 * 64];
  __shared__ __align__(16) ushort Bs[128 * 64];

  const int id = blockIdx.x;
  const int b  = id >> 10;            // batch
  const int t  = id & 1023;
  const int r8 = t & 7;               // XCD swizzle
  const int s2 = t >> 3;
  const int bx = s2 & 31;
  const int by = r8 + ((s2 >> 5) << 3);

  const ushort* A  = qkv + (size_t)b * 4096 * 1536;        // Q rows
  const ushort* Bt = qkv + (size_t)b * 4096 * 1536 + 512;  // K rows
  ushort* C = P + (size_t)b * 4096 * 4096;

  const int tid  = threadIdx.x;
  const int w    = tid >> 6;
  const int lane = tid & 63;
  const int lo   = lane & 15;
  const int quad = lane >> 4;
  const int m0   = by * 128;
  const int n0   = bx * 128;
  const int wm   = (w & 1) * 64;
  const int wn   = (w >> 1) * 64;

  // 1024 16B-chunks per tile: chunk s_ -> row=s_>>3, sl=s_&7; src = sl^(row&7).
  const ushort* gaP[4]; const ushort* gbP[4];
#pragma unroll
  for (int k = 0; k < 4; ++k) {
    const int s_ = tid + k * 256;
    const int row = s_ >> 3, sl = s_ & 7;
    gaP[k] = A  + (size_t)(m0 + row) * 1536 + ((sl ^ (row & 7)) << 3);
    gbP[k] = Bt + (size_t)(n0 + row) * 1536 + ((sl ^ (row & 7)) << 3);
  }

  floatx4 acc[4][4] = {};

  for (int k0 = 0; k0 < 512; k0 += 64) {
    __syncthreads();
#pragma unroll
    for (int k = 0; k < 4; ++k) {
      const int s_ = tid + k * 256;
      __builtin_amdgcn_global_load_lds((const AS1 void*)(gaP[k] + k0), (AS3 void*)(As + s_ * 8), 16, 0, 0);
      __builtin_amdgcn_global_load_lds((const AS1 void*)(gbP[k] + k0), (AS3 void*)(Bs + s_ * 8), 16, 0, 0);
    }
    __syncthreads();

#pragma unroll
    for (int kk = 0; kk < 2; ++kk) {
      short8 af[4], bf[4];
#pragma unroll
      for (int tt = 0; tt < 4; ++tt) {
        const int ra = wm + tt * 16 + lo;
        const int rb = wn + tt * 16 + lo;
        af[tt] = *(const short8*)(As + (size_t)ra * 64 + (((kk * 4 + quad) ^ (ra & 7)) << 3));
        bf[tt] = *(const short8*)(Bs + (size_t)rb * 64 + (((kk * 4 + quad) ^ (rb & 7)) << 3));
      }
#pragma unroll
      for (int mt = 0; mt < 4; ++mt)
#pragma unroll
        for (int nt = 0; nt < 4; ++nt)
          acc[mt][nt] = __builtin_amdgcn_mfma_f32_16x16x32_bf16(af[mt], bf[nt], acc[mt][nt], 0, 0, 0);
    }
  }

#pragma unroll
  for (int mt = 0; mt < 4; ++mt)
#pragma unroll
    for (int r = 0; r < 4; ++r) {
      const int row = m0 + wm + mt * 16 + quad * 4 + r;
#pragma unroll
      for (int nt = 0; nt < 4; ++nt) {
        const int col = n0 + wn + nt * 16 + lo;
        C[(size_t)row * 4096 + col] = f2b(__expf(acc[mt][nt][r] * 0.125f));
      }
    }
}

// Pass C: uni = (P @ VWt)/rs + Wu_b, rs computed inline: rs[row] = P-row . 1
// via mfma(af, ones, rsacc) — each pv block reads its rows' FULL K=4096 slab.
// XCD-panel swizzle: xcd=id&7 owns whole row-panels (col-tiles share its L2).
__global__ __launch_bounds__(256) void gemm_pv_wu(
    const ushort* __restrict__ P, const ushort* __restrict__ vwt,
    const float* __restrict__ bias, ushort* __restrict__ uni)
{
  __shared__ __align__(16) ushort As[128 * 64];
  __shared__ __align__(16) ushort Bs[128 * 64];
  __shared__ float rsm[128];

  const int id  = blockIdx.x;         // 0..511
  const int xcd = id & 7;
  const int s   = id >> 3;            // 0..63
  const int bx  = s & 3;              // col tile
  const int panel = xcd * 16 + (s >> 2);  // 0..127
  const int b  = panel >> 5;
  const int by = panel & 31;

  const ushort* A  = P   + (size_t)b * 4096 * 4096;
  const ushort* Bt = vwt + (size_t)b * 512 * 4096;

  const int tid  = threadIdx.x;
  const int w    = tid >> 6;
  const int lane = tid & 63;
  const int lo   = lane & 15;
  const int quad = lane >> 4;
  const int m0   = by * 128;
  const int n0   = bx * 128;
  const int wm   = (w & 1) * 64;
  const int wn   = (w >> 1) * 64;

  const ushort* gaP[4]; const ushort* gbP[4];
#pragma unroll
  for (int k = 0; k < 4; ++k) {
    const int s_ = tid + k * 256;
    const int row = s_ >> 3, sl = s_ & 7;
    gaP[k] = A  + (size_t)(m0 + row) * 4096 + ((sl ^ (row & 7)) << 3);
    gbP[k] = Bt + (size_t)(n0 + row) * 4096 + ((sl ^ (row & 7)) << 3);
  }

  short8 ones;
#pragma unroll
  for (int j = 0; j < 8; ++j) ones[j] = (short)0x3F80;  // bf16 1.0

  floatx4 acc[4][4] = {};
  floatx4 rsacc[4] = {};

  for (int k0 = 0; k0 < 4096; k0 += 64) {
    __syncthreads();
#pragma unroll
    for (int k = 0; k < 4; ++k) {
      const int s_ = tid + k * 256;
      __builtin_amdgcn_global_load_lds((const AS1 void*)(gaP[k] + k0), (AS3 void*)(As + s_ * 8), 16, 0, 0);
      __builtin_amdgcn_global_load_lds((const AS1 void*)(gbP[k] + k0), (AS3 void*)(Bs + s_ * 8), 16, 0, 0);
    }
    __syncthreads();

#pragma unroll
    for (int kk = 0; kk < 2; ++kk) {
      short8 af[4], bf[4];
#pragma unroll
      for (int tt = 0; tt < 4; ++tt) {
        const int ra = wm + tt * 16 + lo;
        const int rb = wn + tt * 16 + lo;
        af[tt] = *(const short8*)(As + (size_t)ra * 64 + (((kk * 4 + quad) ^ (ra & 7)) << 3));
        bf[tt] = *(const short8*)(Bs + (size_t)rb * 64 + (((kk * 4 + quad) ^ (rb & 7)) << 3));
      }
#pragma unroll
      for (int tt = 0; tt < 4; ++tt)
        rsacc[tt] = __builtin_amdgcn_mfma_f32_16x16x32_bf16(af[tt], ones, rsacc[tt], 0, 0, 0);
#pragma unroll
      for (int mt = 0; mt < 4; ++mt)
#pragma unroll
        for (int nt = 0; nt < 4; ++nt)
          acc[mt][nt] = __builtin_amdgcn_mfma_f32_16x16x32_bf16(af[mt], bf[nt], acc[mt][nt], 0, 0, 0);
    }
  }

  // rsacc[tt][r] = rowsum for local row wm+tt*16+quad*4+r (cols identical, so
  // lo==0 lanes suffice; waves with wn==0 cover wm=0 and wm=64).
  if (wn == 0 && lo == 0) {
#pragma unroll
    for (int tt = 0; tt < 4; ++tt)
#pragma unroll
      for (int r = 0; r < 4; ++r)
        rsm[wm + tt * 16 + quad * 4 + r] = rsacc[tt][r];
  }
  __syncthreads();

#pragma unroll
  for (int mt = 0; mt < 4; ++mt)
#pragma unroll
    for (int r = 0; r < 4; ++r) {
      const int lrow = wm + mt * 16 + quad * 4 + r;
      const size_t grow = (size_t)b * 4096 + m0 + lrow;
      const float inv = 1.f / rsm[lrow];
#pragma unroll
      for (int nt = 0; nt < 4; ++nt) {
        const int col = n0 + wn + nt * 16 + lo;
        uni[grow * 512 + col] = f2b(acc[mt][nt][r] * inv + bias[col]);
      }
    }
}

// ---------------------------------------------------------------------------
// Async NT GEMM, BK=64 XOR-swizzle staging, flat grid with XCD swizzle
// (FF1 / FF2). Same API as the old BK=32 gemm_async.
// ---------------------------------------------------------------------------
__global__ __launch_bounds__(256) void gemm_async64(
    const ushort* __restrict__ A, const ushort* __restrict__ Bt,
    const float* __restrict__ bias, ushort* __restrict__ C,
    int N, int K, int lda, int ldb,
    int lg_gx, int lg_gy, float scale, int flags)
{
  __shared__ __align__(16) ushort As[128 * 64];
  __shared__ __align__(16) ushort Bs[128 * 64];

  const int id = blockIdx.x;
  const int r8 = id & 7;
  const int s  = id >> 3;
  const int bx = s & ((1 << lg_gx) - 1);
  const int j  = r8 + ((s >> lg_gx) << 3);
  const int by = j & ((1 << lg_gy) - 1);

  const int tid  = threadIdx.x;
  const int w    = tid >> 6;
  const int lane = tid & 63;
  const int lo   = lane & 15;
  const int quad = lane >> 4;
  const int m0   = by * 128;
  const int n0   = bx * 128;
  const int wm   = (w & 1) * 64;
  const int wn   = (w >> 1) * 64;

  const ushort* gaP[4]; const ushort* gbP[4];
#pragma unroll
  for (int k = 0; k < 4; ++k) {
    const int s_ = tid + k * 256;
    const int row = s_ >> 3, sl = s_ & 7;
    gaP[k] = A  + (size_t)(m0 + row) * lda + ((sl ^ (row & 7)) << 3);
    gbP[k] = Bt + (size_t)(n0 + row) * ldb + ((sl ^ (row & 7)) << 3);
  }

  floatx4 acc[4][4] = {};

  for (int k0 = 0; k0 < K; k0 += 64) {
    __syncthreads();
#pragma unroll
    for (int k = 0; k < 4; ++k) {
      const int s_ = tid + k * 256;
      __builtin_amdgcn_global_load_lds((const AS1 void*)(gaP[k] + k0), (AS3 void*)(As + s_ * 8), 16, 0, 0);
      __builtin_amdgcn_global_load_lds((const AS1 void*)(gbP[k] + k0), (AS3 void*)(Bs + s_ * 8), 16, 0, 0);
    }
    __syncthreads();

#pragma unroll
    for (int kk = 0; kk < 2; ++kk) {
      short8 af[4], bf[4];
#pragma unroll
      for (int tt = 0; tt < 4; ++tt) {
        const int ra = wm + tt * 16 + lo;
        const int rb = wn + tt * 16 + lo;
        af[tt] = *(const short8*)(As + (size_t)ra * 64 + (((kk * 4 + quad) ^ (ra & 7)) << 3));
        bf[tt] = *(const short8*)(Bs + (size_t)rb * 64 + (((kk * 4 + quad) ^ (rb & 7)) << 3));
      }
#pragma unroll
      for (int mt = 0; mt < 4; ++mt)
#pragma unroll
        for (int nt = 0; nt < 4; ++nt)
          acc[mt][nt] = __builtin_amdgcn_mfma_f32_16x16x32_bf16(af[mt], bf[nt], acc[mt][nt], 0, 0, 0);
    }
  }

#pragma unroll
  for (int mt = 0; mt < 4; ++mt)
#pragma unroll
    for (int nt = 0; nt < 4; ++nt)
#pragma unroll
      for (int r = 0; r < 4; ++r) {
        int row = m0 + wm + mt * 16 + quad * 4 + r;
        int col = n0 + wn + nt * 16 + lo;
        float v = acc[mt][nt][r] * scale;
        if (bias) v += bias[col];
        if (flags & GF_RELU) v = fmaxf(v, 0.f);
        C[(size_t)row * N + col] = f2b(v);
      }
}

// ---------------------------------------------------------------------------
// Sync NT GEMM with fp32 A (cast in staging) — fused QKV projection.
// ---------------------------------------------------------------------------
__global__ __launch_bounds__(256) void gemm_sync_f32a(
    const float* __restrict__ Af, const ushort* __restrict__ Bt,
    const float* __restrict__ bias, ushort* __restrict__ C,
    int N, int K)
{
  __shared__ __align__(16) ushort As[128 * 32];
  __shared__ __align__(16) ushort Bs[128 * 32];

  const int tid  = threadIdx.x;
  const int w    = tid >> 6;
  const int lane = tid & 63;
  const int lo   = lane & 15;
  const int quad = lane >> 4;
  const int m0   = blockIdx.y * 128;
  const int n0   = blockIdx.x * 128;
  const int wm   = (w & 1) * 64;
  const int wn   = (w >> 1) * 64;

  const int i0 = tid, i1 = tid + 256;
  const size_t aoff0 = (size_t)(m0 + (i0 >> 2)) * K + ((i0 & 3) << 3);
  const size_t aoff1 = (size_t)(m0 + (i1 >> 2)) * K + ((i1 & 3) << 3);
  const size_t boff0 = (size_t)(n0 + (i0 >> 2)) * K + ((i0 & 3) << 3);
  const size_t boff1 = (size_t)(n0 + (i1 >> 2)) * K + ((i1 & 3) << 3);

  floatx4 acc[4][4] = {};

  for (int k0 = 0; k0 < K; k0 += 32) {
    short8 va0, va1;
    const float4 a00 = *(const float4*)(Af + aoff0 + k0);
    const float4 a01 = *(const float4*)(Af + aoff0 + k0 + 4);
    const float4 a10 = *(const float4*)(Af + aoff1 + k0);
    const float4 a11 = *(const float4*)(Af + aoff1 + k0 + 4);
    va0[0] = (short)f2b(a00.x); va0[1] = (short)f2b(a00.y);
    va0[2] = (short)f2b(a00.z); va0[3] = (short)f2b(a00.w);
    va0[4] = (short)f2b(a01.x); va0[5] = (short)f2b(a01.y);
    va0[6] = (short)f2b(a01.z); va0[7] = (short)f2b(a01.w);
    va1[0] = (short)f2b(a10.x); va1[1] = (short)f2b(a10.y);
    va1[2] = (short)f2b(a10.z); va1[3] = (short)f2b(a10.w);
    va1[4] = (short)f2b(a11.x); va1[5] = (short)f2b(a11.y);
    va1[6] = (short)f2b(a11.z); va1[7] = (short)f2b(a11.w);
    const short8 vb0 = *(const short8*)(Bt + boff0 + k0);
    const short8 vb1 = *(const short8*)(Bt + boff1 + k0);
    __syncthreads();
    *(short8*)(As + i0 * 8) = va0;
    *(short8*)(As + i1 * 8) = va1;
    *(short8*)(Bs + i0 * 8) = vb0;
    *(short8*)(Bs + i1 * 8) = vb1;
    __syncthreads();

    short8 af[4], bf[4];
#pragma unroll
    for (int t = 0; t < 4; ++t) {
      af[t] = *(const short8*)(As + (wm + t * 16 + lo) * 32 + quad * 8);
      bf[t] = *(const short8*)(Bs + (wn + t * 16 + lo) * 32 + quad * 8);
    }
#pragma unroll
    for (int mt = 0; mt < 4; ++mt)
#pragma unroll
      for (int nt = 0; nt < 4; ++nt)
        acc[mt][nt] = __builtin_amdgcn_mfma_f32_16x16x32_bf16(af[mt], bf[nt], acc[mt][nt], 0, 0, 0);
  }

#pragma unroll
  for (int mt = 0; mt < 4; ++mt)
#pragma unroll
    for (int nt = 0; nt < 4; ++nt)
#pragma unroll
      for (int r = 0; r < 4; ++r) {
        int row = m0 + wm + mt * 16 + quad * 4 + r;
        int col = n0 + wn + nt * 16 + lo;
        C[(size_t)row * N + col] = f2b(acc[mt][nt][r] + bias[col]);
      }
}

// ---------------------------------------------------------------------------
__global__ void transpose_cast(const float* __restrict__ in, ushort* __restrict__ out,
                               int R, int C)
{
  __shared__ ushort t[64][65];
  const int r0 = blockIdx.y * 64, c0 = blockIdx.x * 64;
  const int tx = threadIdx.x, ty = threadIdx.y;
  for (int i = ty; i < 64; i += 4)
    t[i][tx] = f2b(in[(size_t)(r0 + i) * C + c0 + tx]);
  __syncthreads();
  for (int i = ty; i < 64; i += 4)
    out[(size_t)(c0 + i) * R + r0 + tx] = t[tx][i];
}

__global__ void concat_bias(const float* __restrict__ a, const float* __restrict__ b,
                            const float* __restrict__ c, float* __restrict__ o)
{
  const int i = blockIdx.x * 256 + threadIdx.x;
  o[i] = (i < 512) ? a[i] : ((i < 1024) ? b[i - 512] : c[i - 1024]);
}

// ---------------------------------------------------------------------------
// out = LayerNorm(X + Y) * g + b. X fp32/bf16, Y bf16, out fp32/bf16.
// ---------------------------------------------------------------------------
__global__ __launch_bounds__(256) void ln_res(
    const void* __restrict__ Xv, int x_f32, const ushort* __restrict__ Y,
    const float* __restrict__ g, const float* __restrict__ b,
    void* __restrict__ outv, int o_f32)
{
  const int w = threadIdx.x >> 6, lane = threadIdx.x & 63;
  const size_t row = (size_t)blockIdx.x * 4 + w;
  const size_t base = row * 512 + lane * 8;

  float v[8];
  if (x_f32) {
    const float* X = (const float*)Xv + base;
    const float4 x0 = *(const float4*)(X), x1 = *(const float4*)(X + 4);
    v[0] = x0.x; v[1] = x0.y; v[2] = x0.z; v[3] = x0.w;
    v[4] = x1.x; v[5] = x1.y; v[6] = x1.z; v[7] = x1.w;
  } else {
    const short8 xv = *(const short8*)((const ushort*)Xv + base);
#pragma unroll
    for (int j = 0; j < 8; ++j) v[j] = b2f((ushort)xv[j]);
  }
  const short8 yv = *(const short8*)(Y + base);
  float s = 0.f, sq = 0.f;
#pragma unroll
  for (int j = 0; j < 8; ++j) {
    v[j] += b2f((ushort)yv[j]);
    s += v[j]; sq += v[j] * v[j];
  }
  for (int m = 1; m < 64; m <<= 1) {
    s  += __shfl_xor(s,  m, 64);
    sq += __shfl_xor(sq, m, 64);
  }
  const float mean = s * (1.f / 512.f);
  const float var  = sq * (1.f / 512.f) - mean * mean;
  const float rstd = rsqrtf(fmaxf(var, 0.f) + 1e-5f);

  const float4 g0 = *(const float4*)(g + lane * 8);
  const float4 g1 = *(const float4*)(g + lane * 8 + 4);
  const float4 b0 = *(const float4*)(b + lane * 8);
  const float4 b1 = *(const float4*)(b + lane * 8 + 4);
  const float gg[8] = {g0.x, g0.y, g0.z, g0.w, g1.x, g1.y, g1.z, g1.w};
  const float bb[8] = {b0.x, b0.y, b0.z, b0.w, b1.x, b1.y, b1.z, b1.w};

  if (o_f32) {
    float* o = (float*)outv + base;
#pragma unroll
    for (int j = 0; j < 8; ++j) o[j] = (v[j] - mean) * rstd * gg[j] + bb[j];
  } else {
    ushort* o = (ushort*)outv + base;
    short8 ov;
#pragma unroll
    for (int j = 0; j < 8; ++j) ov[j] = (short)f2b((v[j] - mean) * rstd * gg[j] + bb[j]);
    *(short8*)o = ov;
  }
}

// ---------------------------------------------------------------------------
extern "C" void kernel_launch(void* const* d_in, const int* in_sizes, int n_in,
                              void* d_out, int out_size, void* d_ws, size_t ws_size,
                              hipStream_t stream)
{
  const float* x    = (const float*)d_in[0];
  const float* Wq_w = (const float*)d_in[1];
  const float* Wq_b = (const float*)d_in[2];
  const float* Wk_w = (const float*)d_in[3];
  const float* Wk_b = (const float*)d_in[4];
  const float* Wv_w = (const float*)d_in[5];
  const float* Wv_b = (const float*)d_in[6];
  const float* Wu_w = (const float*)d_in[7];
  const float* Wu_b = (const float*)d_in[8];
  const float* g1   = (const float*)d_in[9];
  const float* b1   = (const float*)d_in[10];
  const float* f1w  = (const float*)d_in[11];
  const float* f1b  = (const float*)d_in[12];
  const float* f2w  = (const float*)d_in[13];
  const float* f2bv = (const float*)d_in[14];
  const float* g2   = (const float*)d_in[15];
  const float* b2   = (const float*)d_in[16];

  // Workspace (byte offsets; ws >= 224,401,408 B verified).
  // Attention-phase overlays:
  //   Pbuf bf16 4x4096x4096 at 90,183,680..224,401,408 (h/mid/ffo written after)
  //   uni in the old attn slot (73,406,464) so pv can write while P lives
  char* wsb = (char*)d_ws;
  ushort* wqkvt = (ushort*)(wsb + 0);             // 1536x512   ends   1,572,864
  ushort* wut   = (ushort*)(wsb + 1572864);       //  512x512   ends   2,097,152
  ushort* f1t   = (ushort*)(wsb + 2097152);       // 2048x512   ends   4,194,304
  ushort* f2t   = (ushort*)(wsb + 4194304);       //  512x2048  ends   6,291,456
  float*  bqkv  = (float*) (wsb + 6291456);       // 1536 f32   ends   6,297,600
  ushort* qkv   = (ushort*)(wsb + 6297600);       // 16384x1536 ends  56,629,248
  ushort* vwt   = (ushort*)(wsb + 56629248);      // 4x512x4096 ends  73,406,464
  ushort* uni   = (ushort*)(wsb + 73406464);      // 16384x512  ends  90,183,680
  ushort* h     = (ushort*)(wsb + 106960896);     // 16384x512  ends 123,738,112
  ushort* mid   = (ushort*)(wsb + 123738112);     // 16384x2048 ends 190,846,976
  ushort* ffo   = (ushort*)(wsb + 190846976);     // 16384x512  ends 207,624,192
  ushort* Pbuf  = (ushort*)(wsb + 90183680);      // 134,217,728 B, ends 224,401,408

  const dim3 tb(64, 4);
  transpose_cast<<<dim3(8, 8),  tb, 0, stream>>>(Wq_w, wqkvt,              512, 512);
  transpose_cast<<<dim3(8, 8),  tb, 0, stream>>>(Wk_w, wqkvt + 512 * 512,  512, 512);
  transpose_cast<<<dim3(8, 8),  tb, 0, stream>>>(Wv_w, wqkvt + 1024 * 512, 512, 512);
  transpose_cast<<<dim3(8, 8),  tb, 0, stream>>>(Wu_w, wut, 512, 512);
  transpose_cast<<<dim3(32, 8), tb, 0, stream>>>(f1w, f1t, 512, 2048);
  transpose_cast<<<dim3(8, 32), tb, 0, stream>>>(f2w, f2t, 2048, 512);
  concat_bias<<<6, 256, 0, stream>>>(Wq_b, Wk_b, Wv_b, bqkv);

  // Fused QKV: qkv[16384][1536] = x @ Wqkv^T + b.
  gemm_sync_f32a<<<dim3(12, 128), 256, 0, stream>>>(x, wqkvt, bqkv, qkv, 1536, 512);

  // Attention with fused Wu: VWt -> P -> uni = (P@VWt)/rs + Wu_b (rs inline).
  gemm_vw<<<512, 256, 0, stream>>>(qkv, wut, vwt);
  gemm_qk_exp<<<4096, 256, 0, stream>>>(qkv, Pbuf);
  gemm_pv_wu<<<512, 256, 0, stream>>>(Pbuf, vwt, Wu_b, uni);

  // Residual LN1.
  ln_res<<<4096, 256, 0, stream>>>(x, 1, uni, g1, b1, h, 0);

  // FFN + residual LN2 -> d_out (fp32).
  gemm_async64<<<2048, 256, 0, stream>>>(h, f1t, f1b, mid,
      2048, 512, 512, 512, 4, 7, 1.f, GF_RELU);
  gemm_async64<<<512, 256, 0, stream>>>(mid, f2t, f2bv, ffo,
      512, 2048, 2048, 2048, 2, 7, 1.f, 0);
  ln_res<<<4096, 256, 0, stream>>>(h, 0, ffo, g2, b2, d_out, 1);
}

// Round 9
// 511.973 us; speedup vs baseline: 2.9739x; 1.0002x over previous
//
#include <hip/hip_runtime.h>

#define AS1 __attribute__((address_space(1)))
#define AS3 __attribute__((address_space(3)))

typedef __attribute__((ext_vector_type(8))) short short8;
typedef __attribute__((ext_vector_type(4))) float floatx4;

__device__ __forceinline__ float b2f(ushort u) {
  union { unsigned int i; float f; } x; x.i = ((unsigned int)u) << 16; return x.f;
}
__device__ __forceinline__ ushort f2b(float f) {
  union { float f; unsigned int i; } x; x.f = f;
  unsigned int r = (x.i + 0x7fffu + ((x.i >> 16) & 1u)) >> 16;
  return (ushort)r;
}

#define GF_RELU 1

// ---------------------------------------------------------------------------
// v9 (from v8 = 512us; qk 105us MfmaUtil 27.6 VALU 33 FETCH 138MB conflicts 0):
//  - qk_exp XCD remap: xcd owns (batch-half x all bx), by sweeps fastest ->
//    K-panel reused 16x inside the in-flight window, Q resident. FETCH
//    138MB (8.6x ideal) -> ~50MB predicted.
//  - LDS-bounce epilogue (qk/FF/QKV): C-tile staged into the dead 32KB
//    As+Bs LDS (XOR chunk swizzle), stored as coalesced short8 — 64 scalar
//    2B stores/thread -> 8 vector 16B stores. One extra barrier pair.
//  - QKV projection: x pre-cast to bf16 (into dead Pbuf region) + async64
//    structure (replaces BK=32 gemm_sync_f32a).
//  - pv_wu / vw / ln_res unchanged (v8-proven).
// ---------------------------------------------------------------------------

// Pass A: VWt[b][c][j] = sum_d Wu[d][c] * V[b][j][d].  (tiny; BK=32 skeleton)
__global__ __launch_bounds__(256) void gemm_vw(
    const ushort* __restrict__ qkv, const ushort* __restrict__ wut,
    ushort* __restrict__ vwt)
{
  __shared__ __align__(16) ushort As[128 * 32];
  __shared__ __align__(16) ushort Bs[128 * 32];

  const int id = blockIdx.x;
  const int b  = id >> 7;
  const int t  = id & 127;
  const int bx = t & 31;              // j tile
  const int by = t >> 5;              // c tile

  const ushort* A  = wut;
  const ushort* Bt = qkv + (size_t)b * 4096 * 1536 + 1024;
  ushort* C = vwt + (size_t)b * 512 * 4096;

  const int tid  = threadIdx.x;
  const int w    = tid >> 6;
  const int lane = tid & 63;
  const int lo   = lane & 15;
  const int quad = lane >> 4;
  const int m0   = by * 128;
  const int n0   = bx * 128;
  const int wm   = (w & 1) * 64;
  const int wn   = (w >> 1) * 64;

  const int i0 = tid, i1 = tid + 256;
  const ushort* ga0 = A  + (size_t)(m0 + (i0 >> 2)) * 512 + ((i0 & 3) << 3);
  const ushort* ga1 = A  + (size_t)(m0 + (i1 >> 2)) * 512 + ((i1 & 3) << 3);
  const ushort* gb0 = Bt + (size_t)(n0 + (i0 >> 2)) * 1536 + ((i0 & 3) << 3);
  const ushort* gb1 = Bt + (size_t)(n0 + (i1 >> 2)) * 1536 + ((i1 & 3) << 3);

  floatx4 acc[4][4] = {};

  for (int k0 = 0; k0 < 512; k0 += 32) {
    __syncthreads();
    __builtin_amdgcn_global_load_lds((const AS1 void*)(ga0 + k0), (AS3 void*)(As + i0 * 8), 16, 0, 0);
    __builtin_amdgcn_global_load_lds((const AS1 void*)(ga1 + k0), (AS3 void*)(As + i1 * 8), 16, 0, 0);
    __builtin_amdgcn_global_load_lds((const AS1 void*)(gb0 + k0), (AS3 void*)(Bs + i0 * 8), 16, 0, 0);
    __builtin_amdgcn_global_load_lds((const AS1 void*)(gb1 + k0), (AS3 void*)(Bs + i1 * 8), 16, 0, 0);
    __syncthreads();

    short8 af[4], bf[4];
#pragma unroll
    for (int tt = 0; tt < 4; ++tt) {
      af[tt] = *(const short8*)(As + (wm + tt * 16 + lo) * 32 + quad * 8);
      bf[tt] = *(const short8*)(Bs + (wn + tt * 16 + lo) * 32 + quad * 8);
    }
#pragma unroll
    for (int mt = 0; mt < 4; ++mt)
#pragma unroll
      for (int nt = 0; nt < 4; ++nt)
        acc[mt][nt] = __builtin_amdgcn_mfma_f32_16x16x32_bf16(af[mt], bf[nt], acc[mt][nt], 0, 0, 0);
  }

#pragma unroll
  for (int mt = 0; mt < 4; ++mt)
#pragma unroll
    for (int nt = 0; nt < 4; ++nt)
#pragma unroll
      for (int r = 0; r < 4; ++r) {
        const int row = m0 + wm + mt * 16 + quad * 4 + r;
        const int col = n0 + wn + nt * 16 + lo;
        C[(size_t)row * 4096 + col] = f2b(acc[mt][nt][r]);
      }
}

// Pass B: P = exp((Q.K^T)/8). BK=64 XOR-swizzle staging; LDS-bounce coalesced
// epilogue. XCD rectangle map: xcd = id&7 owns (batch = xcd>>1, by-half =
// xcd&1) x all bx; by sweeps fastest so the in-flight window reuses each
// K-panel ~16x and keeps Q (2MB) L2-resident.
__global__ __launch_bounds__(256) void gemm_qk_exp(
    const ushort* __restrict__ qkv, ushort* __restrict__ P)
{
  __shared__ __align__(16) ushort smem[128 * 128];  // As | Bs, then C bounce
  ushort* As = smem;
  ushort* Bs = smem + 128 * 64;

  const int id  = blockIdx.x;         // 0..4095
  const int xcd = id & 7;
  const int s   = id >> 3;            // 0..511
  const int b   = xcd >> 1;           // batch
  const int by  = (xcd & 1) * 16 + (s & 15);
  const int bx  = s >> 4;             // 0..31

  const ushort* A  = qkv + (size_t)b * 4096 * 1536;        // Q rows
  const ushort* Bt = qkv + (size_t)b * 4096 * 1536 + 512;  // K rows
  ushort* C = P + (size_t)b * 4096 * 4096;

  const int tid  = threadIdx.x;
  const int w    = tid >> 6;
  const int lane = tid & 63;
  const int lo   = lane & 15;
  const int quad = lane >> 4;
  const int m0   = by * 128;
  const int n0   = bx * 128;
  const int wm   = (w & 1) * 64;
  const int wn   = (w >> 1) * 64;

  // 1024 16B-chunks per tile: chunk s_ -> row=s_>>3, sl=s_&7; src = sl^(row&7).
  const ushort* gaP[4]; const ushort* gbP[4];
#pragma unroll
  for (int k = 0; k < 4; ++k) {
    const int s_ = tid + k * 256;
    const int row = s_ >> 3, sl = s_ & 7;
    gaP[k] = A  + (size_t)(m0 + row) * 1536 + ((sl ^ (row & 7)) << 3);
    gbP[k] = Bt + (size_t)(n0 + row) * 1536 + ((sl ^ (row & 7)) << 3);
  }

  floatx4 acc[4][4] = {};

  for (int k0 = 0; k0 < 512; k0 += 64) {
    __syncthreads();
#pragma unroll
    for (int k = 0; k < 4; ++k) {
      const int s_ = tid + k * 256;
      __builtin_amdgcn_global_load_lds((const AS1 void*)(gaP[k] + k0), (AS3 void*)(As + s_ * 8), 16, 0, 0);
      __builtin_amdgcn_global_load_lds((const AS1 void*)(gbP[k] + k0), (AS3 void*)(Bs + s_ * 8), 16, 0, 0);
    }
    __syncthreads();

#pragma unroll
    for (int kk = 0; kk < 2; ++kk) {
      short8 af[4], bf[4];
#pragma unroll
      for (int tt = 0; tt < 4; ++tt) {
        const int ra = wm + tt * 16 + lo;
        const int rb = wn + tt * 16 + lo;
        af[tt] = *(const short8*)(As + (size_t)ra * 64 + (((kk * 4 + quad) ^ (ra & 7)) << 3));
        bf[tt] = *(const short8*)(Bs + (size_t)rb * 64 + (((kk * 4 + quad) ^ (rb & 7)) << 3));
      }
#pragma unroll
      for (int mt = 0; mt < 4; ++mt)
#pragma unroll
        for (int nt = 0; nt < 4; ++nt)
          acc[mt][nt] = __builtin_amdgcn_mfma_f32_16x16x32_bf16(af[mt], bf[nt], acc[mt][nt], 0, 0, 0);
    }
  }

  // LDS-bounce epilogue: exp -> smem (XOR chunk swizzle) -> coalesced short8.
  __syncthreads();
#pragma unroll
  for (int mt = 0; mt < 4; ++mt)
#pragma unroll
    for (int r = 0; r < 4; ++r) {
      const int row = wm + mt * 16 + quad * 4 + r;
#pragma unroll
      for (int nt = 0; nt < 4; ++nt) {
        const int col = wn + nt * 16 + lo;
        smem[row * 128 + ((((col >> 3) ^ (row & 7)) << 3) | (col & 7))] =
            f2b(__expf(acc[mt][nt][r] * 0.125f));
      }
    }
  __syncthreads();
#pragma unroll
  for (int k = 0; k < 8; ++k) {
    const int c = tid + k * 256;
    const int row = c >> 4, c16 = c & 15;
    const short8 v = *(const short8*)(smem + row * 128 + ((c16 ^ (row & 7)) << 3));
    *(short8*)(C + (size_t)(m0 + row) * 4096 + n0 + c16 * 8) = v;
  }
}

// Pass C: uni = (P @ VWt)/rs + Wu_b, rs computed inline: rs[row] = P-row . 1
// via mfma(af, ones, rsacc). XCD-panel swizzle (v7/v8-proven). Unchanged.
__global__ __launch_bounds__(256) void gemm_pv_wu(
    const ushort* __restrict__ P, const ushort* __restrict__ vwt,
    const float* __restrict__ bias, ushort* __restrict__ uni)
{
  __shared__ __align__(16) ushort As[128 * 64];
  __shared__ __align__(16) ushort Bs[128 * 64];
  __shared__ float rsm[128];

  const int id  = blockIdx.x;         // 0..511
  const int xcd = id & 7;
  const int s   = id >> 3;            // 0..63
  const int bx  = s & 3;              // col tile
  const int panel = xcd * 16 + (s >> 2);  // 0..127
  const int b  = panel >> 5;
  const int by = panel & 31;

  const ushort* A  = P   + (size_t)b * 4096 * 4096;
  const ushort* Bt = vwt + (size_t)b * 512 * 4096;

  const int tid  = threadIdx.x;
  const int w    = tid >> 6;
  const int lane = tid & 63;
  const int lo   = lane & 15;
  const int quad = lane >> 4;
  const int m0   = by * 128;
  const int n0   = bx * 128;
  const int wm   = (w & 1) * 64;
  const int wn   = (w >> 1) * 64;

  const ushort* gaP[4]; const ushort* gbP[4];
#pragma unroll
  for (int k = 0; k < 4; ++k) {
    const int s_ = tid + k * 256;
    const int row = s_ >> 3, sl = s_ & 7;
    gaP[k] = A  + (size_t)(m0 + row) * 4096 + ((sl ^ (row & 7)) << 3);
    gbP[k] = Bt + (size_t)(n0 + row) * 4096 + ((sl ^ (row & 7)) << 3);
  }

  short8 ones;
#pragma unroll
  for (int j = 0; j < 8; ++j) ones[j] = (short)0x3F80;  // bf16 1.0

  floatx4 acc[4][4] = {};
  floatx4 rsacc[4] = {};

  for (int k0 = 0; k0 < 4096; k0 += 64) {
    __syncthreads();
#pragma unroll
    for (int k = 0; k < 4; ++k) {
      const int s_ = tid + k * 256;
      __builtin_amdgcn_global_load_lds((const AS1 void*)(gaP[k] + k0), (AS3 void*)(As + s_ * 8), 16, 0, 0);
      __builtin_amdgcn_global_load_lds((const AS1 void*)(gbP[k] + k0), (AS3 void*)(Bs + s_ * 8), 16, 0, 0);
    }
    __syncthreads();

#pragma unroll
    for (int kk = 0; kk < 2; ++kk) {
      short8 af[4], bf[4];
#pragma unroll
      for (int tt = 0; tt < 4; ++tt) {
        const int ra = wm + tt * 16 + lo;
        const int rb = wn + tt * 16 + lo;
        af[tt] = *(const short8*)(As + (size_t)ra * 64 + (((kk * 4 + quad) ^ (ra & 7)) << 3));
        bf[tt] = *(const short8*)(Bs + (size_t)rb * 64 + (((kk * 4 + quad) ^ (rb & 7)) << 3));
      }
#pragma unroll
      for (int tt = 0; tt < 4; ++tt)
        rsacc[tt] = __builtin_amdgcn_mfma_f32_16x16x32_bf16(af[tt], ones, rsacc[tt], 0, 0, 0);
#pragma unroll
      for (int mt = 0; mt < 4; ++mt)
#pragma unroll
        for (int nt = 0; nt < 4; ++nt)
          acc[mt][nt] = __builtin_amdgcn_mfma_f32_16x16x32_bf16(af[mt], bf[nt], acc[mt][nt], 0, 0, 0);
    }
  }

  if (wn == 0 && lo == 0) {
#pragma unroll
    for (int tt = 0; tt < 4; ++tt)
#pragma unroll
      for (int r = 0; r < 4; ++r)
        rsm[wm + tt * 16 + quad * 4 + r] = rsacc[tt][r];
  }
  __syncthreads();

#pragma unroll
  for (int mt = 0; mt < 4; ++mt)
#pragma unroll
    for (int r = 0; r < 4; ++r) {
      const int lrow = wm + mt * 16 + quad * 4 + r;
      const size_t grow = (size_t)b * 4096 + m0 + lrow;
      const float inv = 1.f / rsm[lrow];
#pragma unroll
      for (int nt = 0; nt < 4; ++nt) {
        const int col = n0 + wn + nt * 16 + lo;
        uni[grow * 512 + col] = f2b(acc[mt][nt][r] * inv + bias[col]);
      }
    }
}

// ---------------------------------------------------------------------------
// Async NT GEMM, BK=64 XOR-swizzle staging + LDS-bounce epilogue, flat grid
// with XCD swizzle (FF1 / FF2).
// ---------------------------------------------------------------------------
__global__ __launch_bounds__(256) void gemm_async64(
    const ushort* __restrict__ A, const ushort* __restrict__ Bt,
    const float* __restrict__ bias, ushort* __restrict__ C,
    int N, int K, int lda, int ldb,
    int lg_gx, int lg_gy, float scale, int flags)
{
  __shared__ __align__(16) ushort smem[128 * 128];
  ushort* As = smem;
  ushort* Bs = smem + 128 * 64;

  const int id = blockIdx.x;
  const int r8 = id & 7;
  const int s  = id >> 3;
  const int bx = s & ((1 << lg_gx) - 1);
  const int j  = r8 + ((s >> lg_gx) << 3);
  const int by = j & ((1 << lg_gy) - 1);

  const int tid  = threadIdx.x;
  const int w    = tid >> 6;
  const int lane = tid & 63;
  const int lo   = lane & 15;
  const int quad = lane >> 4;
  const int m0   = by * 128;
  const int n0   = bx * 128;
  const int wm   = (w & 1) * 64;
  const int wn   = (w >> 1) * 64;

  const ushort* gaP[4]; const ushort* gbP[4];
#pragma unroll
  for (int k = 0; k < 4; ++k) {
    const int s_ = tid + k * 256;
    const int row = s_ >> 3, sl = s_ & 7;
    gaP[k] = A  + (size_t)(m0 + row) * lda + ((sl ^ (row & 7)) << 3);
    gbP[k] = Bt + (size_t)(n0 + row) * ldb + ((sl ^ (row & 7)) << 3);
  }

  floatx4 acc[4][4] = {};

  for (int k0 = 0; k0 < K; k0 += 64) {
    __syncthreads();
#pragma unroll
    for (int k = 0; k < 4; ++k) {
      const int s_ = tid + k * 256;
      __builtin_amdgcn_global_load_lds((const AS1 void*)(gaP[k] + k0), (AS3 void*)(As + s_ * 8), 16, 0, 0);
      __builtin_amdgcn_global_load_lds((const AS1 void*)(gbP[k] + k0), (AS3 void*)(Bs + s_ * 8), 16, 0, 0);
    }
    __syncthreads();

#pragma unroll
    for (int kk = 0; kk < 2; ++kk) {
      short8 af[4], bf[4];
#pragma unroll
      for (int tt = 0; tt < 4; ++tt) {
        const int ra = wm + tt * 16 + lo;
        const int rb = wn + tt * 16 + lo;
        af[tt] = *(const short8*)(As + (size_t)ra * 64 + (((kk * 4 + quad) ^ (ra & 7)) << 3));
        bf[tt] = *(const short8*)(Bs + (size_t)rb * 64 + (((kk * 4 + quad) ^ (rb & 7)) << 3));
      }
#pragma unroll
      for (int mt = 0; mt < 4; ++mt)
#pragma unroll
        for (int nt = 0; nt < 4; ++nt)
          acc[mt][nt] = __builtin_amdgcn_mfma_f32_16x16x32_bf16(af[mt], bf[nt], acc[mt][nt], 0, 0, 0);
    }
  }

  // LDS-bounce epilogue.
  __syncthreads();
#pragma unroll
  for (int mt = 0; mt < 4; ++mt)
#pragma unroll
    for (int r = 0; r < 4; ++r) {
      const int row = wm + mt * 16 + quad * 4 + r;
#pragma unroll
      for (int nt = 0; nt < 4; ++nt) {
        const int col = wn + nt * 16 + lo;
        float v = acc[mt][nt][r] * scale;
        if (bias) v += bias[n0 + col];
        if (flags & GF_RELU) v = fmaxf(v, 0.f);
        smem[row * 128 + ((((col >> 3) ^ (row & 7)) << 3) | (col & 7))] = f2b(v);
      }
    }
  __syncthreads();
#pragma unroll
  for (int k = 0; k < 8; ++k) {
    const int c = tid + k * 256;
    const int row = c >> 4, c16 = c & 15;
    const short8 v = *(const short8*)(smem + row * 128 + ((c16 ^ (row & 7)) << 3));
    *(short8*)(C + (size_t)(m0 + row) * N + n0 + c16 * 8) = v;
  }
}

// ---------------------------------------------------------------------------
// QKV projection: same structure as gemm_async64 but dim3 grid (N=1536 has 12
// col tiles, not a power of 2). A is pre-cast bf16 x.
// ---------------------------------------------------------------------------
__global__ __launch_bounds__(256) void gemm_qkv(
    const ushort* __restrict__ A, const ushort* __restrict__ Bt,
    const float* __restrict__ bias, ushort* __restrict__ C)
{
  __shared__ __align__(16) ushort smem[128 * 128];
  ushort* As = smem;
  ushort* Bs = smem + 128 * 64;

  const int bx = blockIdx.x;          // 0..11
  const int by = blockIdx.y;          // 0..127

  const int tid  = threadIdx.x;
  const int w    = tid >> 6;
  const int lane = tid & 63;
  const int lo   = lane & 15;
  const int quad = lane >> 4;
  const int m0   = by * 128;
  const int n0   = bx * 128;
  const int wm   = (w & 1) * 64;
  const int wn   = (w >> 1) * 64;

  const ushort* gaP[4]; const ushort* gbP[4];
#pragma unroll
  for (int k = 0; k < 4; ++k) {
    const int s_ = tid + k * 256;
    const int row = s_ >> 3, sl = s_ & 7;
    gaP[k] = A  + (size_t)(m0 + row) * 512 + ((sl ^ (row & 7)) << 3);
    gbP[k] = Bt + (size_t)(n0 + row) * 512 + ((sl ^ (row & 7)) << 3);
  }

  floatx4 acc[4][4] = {};

  for (int k0 = 0; k0 < 512; k0 += 64) {
    __syncthreads();
#pragma unroll
    for (int k = 0; k < 4; ++k) {
      const int s_ = tid + k * 256;
      __builtin_amdgcn_global_load_lds((const AS1 void*)(gaP[k] + k0), (AS3 void*)(As + s_ * 8), 16, 0, 0);
      __builtin_amdgcn_global_load_lds((const AS1 void*)(gbP[k] + k0), (AS3 void*)(Bs + s_ * 8), 16, 0, 0);
    }
    __syncthreads();

#pragma unroll
    for (int kk = 0; kk < 2; ++kk) {
      short8 af[4], bf[4];
#pragma unroll
      for (int tt = 0; tt < 4; ++tt) {
        const int ra = wm + tt * 16 + lo;
        const int rb = wn + tt * 16 + lo;
        af[tt] = *(const short8*)(As + (size_t)ra * 64 + (((kk * 4 + quad) ^ (ra & 7)) << 3));
        bf[tt] = *(const short8*)(Bs + (size_t)rb * 64 + (((kk * 4 + quad) ^ (rb & 7)) << 3));
      }
#pragma unroll
      for (int mt = 0; mt < 4; ++mt)
#pragma unroll
        for (int nt = 0; nt < 4; ++nt)
          acc[mt][nt] = __builtin_amdgcn_mfma_f32_16x16x32_bf16(af[mt], bf[nt], acc[mt][nt], 0, 0, 0);
    }
  }

  __syncthreads();
#pragma unroll
  for (int mt = 0; mt < 4; ++mt)
#pragma unroll
    for (int r = 0; r < 4; ++r) {
      const int row = wm + mt * 16 + quad * 4 + r;
#pragma unroll
      for (int nt = 0; nt < 4; ++nt) {
        const int col = wn + nt * 16 + lo;
        smem[row * 128 + ((((col >> 3) ^ (row & 7)) << 3) | (col & 7))] =
            f2b(acc[mt][nt][r] + bias[n0 + col]);
      }
    }
  __syncthreads();
#pragma unroll
  for (int k = 0; k < 8; ++k) {
    const int c = tid + k * 256;
    const int row = c >> 4, c16 = c & 15;
    const short8 v = *(const short8*)(smem + row * 128 + ((c16 ^ (row & 7)) << 3));
    *(short8*)(C + (size_t)(m0 + row) * 1536 + n0 + c16 * 8) = v;
  }
}

// x fp32 -> bf16 (pre-cast for QKV GEMM).
__global__ __launch_bounds__(256) void cast_f32_bf16(
    const float* __restrict__ in, ushort* __restrict__ out)
{
  const size_t i = ((size_t)blockIdx.x * 256 + threadIdx.x) * 8;
  const float4 a = *(const float4*)(in + i);
  const float4 b = *(const float4*)(in + i + 4);
  short8 v;
  v[0] = (short)f2b(a.x); v[1] = (short)f2b(a.y);
  v[2] = (short)f2b(a.z); v[3] = (short)f2b(a.w);
  v[4] = (short)f2b(b.x); v[5] = (short)f2b(b.y);
  v[6] = (short)f2b(b.z); v[7] = (short)f2b(b.w);
  *(short8*)(out + i) = v;
}

// ---------------------------------------------------------------------------
__global__ void transpose_cast(const float* __restrict__ in, ushort* __restrict__ out,
                               int R, int C)
{
  __shared__ ushort t[64][65];
  const int r0 = blockIdx.y * 64, c0 = blockIdx.x * 64;
  const int tx = threadIdx.x, ty = threadIdx.y;
  for (int i = ty; i < 64; i += 4)
    t[i][tx] = f2b(in[(size_t)(r0 + i) * C + c0 + tx]);
  __syncthreads();
  for (int i = ty; i < 64; i += 4)
    out[(size_t)(c0 + i) * R + r0 + tx] = t[tx][i];
}

__global__ void concat_bias(const float* __restrict__ a, const float* __restrict__ b,
                            const float* __restrict__ c, float* __restrict__ o)
{
  const int i = blockIdx.x * 256 + threadIdx.x;
  o[i] = (i < 512) ? a[i] : ((i < 1024) ? b[i - 512] : c[i - 1024]);
}

// ---------------------------------------------------------------------------
// out = LayerNorm(X + Y) * g + b. X fp32/bf16, Y bf16, out fp32/bf16.
// ---------------------------------------------------------------------------
__global__ __launch_bounds__(256) void ln_res(
    const void* __restrict__ Xv, int x_f32, const ushort* __restrict__ Y,
    const float* __restrict__ g, const float* __restrict__ b,
    void* __restrict__ outv, int o_f32)
{
  const int w = threadIdx.x >> 6, lane = threadIdx.x & 63;
  const size_t row = (size_t)blockIdx.x * 4 + w;
  const size_t base = row * 512 + lane * 8;

  float v[8];
  if (x_f32) {
    const float* X = (const float*)Xv + base;
    const float4 x0 = *(const float4*)(X), x1 = *(const float4*)(X + 4);
    v[0] = x0.x; v[1] = x0.y; v[2] = x0.z; v[3] = x0.w;
    v[4] = x1.x; v[5] = x1.y; v[6] = x1.z; v[7] = x1.w;
  } else {
    const short8 xv = *(const short8*)((const ushort*)Xv + base);
#pragma unroll
    for (int j = 0; j < 8; ++j) v[j] = b2f((ushort)xv[j]);
  }
  const short8 yv = *(const short8*)(Y + base);
  float s = 0.f, sq = 0.f;
#pragma unroll
  for (int j = 0; j < 8; ++j) {
    v[j] += b2f((ushort)yv[j]);
    s += v[j]; sq += v[j] * v[j];
  }
  for (int m = 1; m < 64; m <<= 1) {
    s  += __shfl_xor(s,  m, 64);
    sq += __shfl_xor(sq, m, 64);
  }
  const float mean = s * (1.f / 512.f);
  const float var  = sq * (1.f / 512.f) - mean * mean;
  const float rstd = rsqrtf(fmaxf(var, 0.f) + 1e-5f);

  const float4 g0 = *(const float4*)(g + lane * 8);
  const float4 g1 = *(const float4*)(g + lane * 8 + 4);
  const float4 b0 = *(const float4*)(b + lane * 8);
  const float4 b1 = *(const float4*)(b + lane * 8 + 4);
  const float gg[8] = {g0.x, g0.y, g0.z, g0.w, g1.x, g1.y, g1.z, g1.w};
  const float bb[8] = {b0.x, b0.y, b0.z, b0.w, b1.x, b1.y, b1.z, b1.w};

  if (o_f32) {
    float* o = (float*)outv + base;
#pragma unroll
    for (int j = 0; j < 8; ++j) o[j] = (v[j] - mean) * rstd * gg[j] + bb[j];
  } else {
    ushort* o = (ushort*)outv + base;
    short8 ov;
#pragma unroll
    for (int j = 0; j < 8; ++j) ov[j] = (short)f2b((v[j] - mean) * rstd * gg[j] + bb[j]);
    *(short8*)o = ov;
  }
}

// ---------------------------------------------------------------------------
extern "C" void kernel_launch(void* const* d_in, const int* in_sizes, int n_in,
                              void* d_out, int out_size, void* d_ws, size_t ws_size,
                              hipStream_t stream)
{
  const float* x    = (const float*)d_in[0];
  const float* Wq_w = (const float*)d_in[1];
  const float* Wq_b = (const float*)d_in[2];
  const float* Wk_w = (const float*)d_in[3];
  const float* Wk_b = (const float*)d_in[4];
  const float* Wv_w = (const float*)d_in[5];
  const float* Wv_b = (const float*)d_in[6];
  const float* Wu_w = (const float*)d_in[7];
  const float* Wu_b = (const float*)d_in[8];
  const float* g1   = (const float*)d_in[9];
  const float* b1   = (const float*)d_in[10];
  const float* f1w  = (const float*)d_in[11];
  const float* f1b  = (const float*)d_in[12];
  const float* f2w  = (const float*)d_in[13];
  const float* f2bv = (const float*)d_in[14];
  const float* g2   = (const float*)d_in[15];
  const float* b2   = (const float*)d_in[16];

  // Workspace (byte offsets; ws >= 224,401,408 B verified).
  // Attention-phase overlays:
  //   xb bf16 x at Pbuf start (dead once qk_exp writes P)
  //   Pbuf bf16 4x4096x4096 at 90,183,680..224,401,408 (h/mid/ffo written after)
  //   uni in the old attn slot (73,406,464) so pv can write while P lives
  char* wsb = (char*)d_ws;
  ushort* wqkvt = (ushort*)(wsb + 0);             // 1536x512   ends   1,572,864
  ushort* wut   = (ushort*)(wsb + 1572864);       //  512x512   ends   2,097,152
  ushort* f1t   = (ushort*)(wsb + 2097152);       // 2048x512   ends   4,194,304
  ushort* f2t   = (ushort*)(wsb + 4194304);       //  512x2048  ends   6,291,456
  float*  bqkv  = (float*) (wsb + 6291456);       // 1536 f32   ends   6,297,600
  ushort* qkv   = (ushort*)(wsb + 6297600);       // 16384x1536 ends  56,629,248
  ushort* vwt   = (ushort*)(wsb + 56629248);      // 4x512x4096 ends  73,406,464
  ushort* uni   = (ushort*)(wsb + 73406464);      // 16384x512  ends  90,183,680
  ushort* h     = (ushort*)(wsb + 106960896);     // 16384x512  ends 123,738,112
  ushort* mid   = (ushort*)(wsb + 123738112);     // 16384x2048 ends 190,846,976
  ushort* ffo   = (ushort*)(wsb + 190846976);     // 16384x512  ends 207,624,192
  ushort* Pbuf  = (ushort*)(wsb + 90183680);      // 134,217,728 B, ends 224,401,408
  ushort* xb    = (ushort*)(wsb + 90183680);      // 16,777,216 B (pre-qk only)

  const dim3 tb(64, 4);
  transpose_cast<<<dim3(8, 8),  tb, 0, stream>>>(Wq_w, wqkvt,              512, 512);
  transpose_cast<<<dim3(8, 8),  tb, 0, stream>>>(Wk_w, wqkvt + 512 * 512,  512, 512);
  transpose_cast<<<dim3(8, 8),  tb, 0, stream>>>(Wv_w, wqkvt + 1024 * 512, 512, 512);
  transpose_cast<<<dim3(8, 8),  tb, 0, stream>>>(Wu_w, wut, 512, 512);
  transpose_cast<<<dim3(32, 8), tb, 0, stream>>>(f1w, f1t, 512, 2048);
  transpose_cast<<<dim3(8, 32), tb, 0, stream>>>(f2w, f2t, 2048, 512);
  concat_bias<<<6, 256, 0, stream>>>(Wq_b, Wk_b, Wv_b, bqkv);

  // Fused QKV: cast x -> bf16, then async BK=64 GEMM with bounce epilogue.
  cast_f32_bf16<<<4096, 256, 0, stream>>>(x, xb);
  gemm_qkv<<<dim3(12, 128), 256, 0, stream>>>(xb, wqkvt, bqkv, qkv);

  // Attention with fused Wu: VWt -> P -> uni = (P@VWt)/rs + Wu_b (rs inline).
  gemm_vw<<<512, 256, 0, stream>>>(qkv, wut, vwt);
  gemm_qk_exp<<<4096, 256, 0, stream>>>(qkv, Pbuf);
  gemm_pv_wu<<<512, 256, 0, stream>>>(Pbuf, vwt, Wu_b, uni);

  // Residual LN1.
  ln_res<<<4096, 256, 0, stream>>>(x, 1, uni, g1, b1, h, 0);

  // FFN + residual LN2 -> d_out (fp32).
  gemm_async64<<<2048, 256, 0, stream>>>(h, f1t, f1b, mid,
      2048, 512, 512, 512, 4, 7, 1.f, GF_RELU);
  gemm_async64<<<512, 256, 0, stream>>>(mid, f2t, f2bv, ffo,
      512, 2048, 2048, 2048, 2, 7, 1.f, 0);
  ln_res<<<4096, 256, 0, stream>>>(h, 0, ffo, g2, b2, d_out, 1);
}